// Round 1
// baseline (1415.591 us; speedup 1.0000x reference)
//
#include <hip/hip_runtime.h>

#define BLK 256
#define NEG_SLOPE 0.2f

static inline int cdiv(long long a, long long b) { return (int)((a + b - 1) / b); }

// ---------------------------------------------------------------------------
// Detect whether edge_index is stored as int64 (reference dtype) or int32
// (harness "integer -> const int*" contract). Reading the first 512 entries
// as int64: if ALL land in [0, n) the buffer is int64 (high words all zero,
// probability ~0 for int32 data where "high words" are real random indices).
// ---------------------------------------------------------------------------
__global__ void detect_i64_kernel(const void* ei_raw, int E_, int n, int* flag)
{
    if (blockIdx.x == 0 && threadIdx.x == 0) {
        const long long* e64 = (const long long*)ei_raw;
        int cnt = E_ < 512 ? E_ : 512;
        int ok = 1;
        for (int i = 0; i < cnt; i++) {
            long long v = e64[i];
            if (v < 0 || v >= n) { ok = 0; break; }
        }
        *flag = ok;
    }
}

__device__ __forceinline__ void load_sd(const void* ei_raw, int is64, int e, int E_,
                                        int& s, int& d)
{
    if (is64) {
        const long long* p = (const long long*)ei_raw;
        s = (int)p[e];
        d = (int)p[E_ + e];
    } else {
        const int* p = (const int*)ei_raw;
        s = p[e];
        d = p[E_ + e];
    }
}

// ---------------------------------------------------------------------------
// h = x @ W   (x: [n, INC], W: [INC, OUTC] row-major, h: [n, OUTC])
// W cached in LDS; each thread computes one output column j for NPT nodes
// (cuts LDS reads per FMA by NPT).
// ---------------------------------------------------------------------------
template <int INC, int OUTC, int NPT>
__global__ __launch_bounds__(BLK) void gemm_kernel(const float* __restrict__ x,
                                                   const float* __restrict__ W,
                                                   float* __restrict__ h, int n)
{
    __shared__ float Wl[INC * OUTC];
    for (int i = threadIdx.x; i < INC * OUTC; i += BLK) Wl[i] = W[i];
    __syncthreads();

    int gid = blockIdx.x * BLK + threadIdx.x;
    int j = gid % OUTC;
    int g = gid / OUTC;
    int n0 = g * NPT;
    if (n0 >= n) return;

    float acc[NPT];
#pragma unroll
    for (int t = 0; t < NPT; t++) acc[t] = 0.f;

    const float* xr = x + (size_t)n0 * INC;
#pragma unroll 4
    for (int k = 0; k < INC; k++) {
        float w = Wl[k * OUTC + j];
#pragma unroll
        for (int t = 0; t < NPT; t++) acc[t] += xr[(size_t)t * INC + k] * w;
    }
#pragma unroll
    for (int t = 0; t < NPT; t++) {
        if (n0 + t < n) h[(size_t)(n0 + t) * OUTC + j] = acc[t];
    }
}

// ---------------------------------------------------------------------------
// a_src[n,h] = sum_c h[n,h,c]*att_src[h,c] ; a_dst likewise. One thread per
// (node, head). H = 4 for all layers.
// ---------------------------------------------------------------------------
__global__ __launch_bounds__(BLK) void attn_kernel(const float* __restrict__ h,
                                                   const float* __restrict__ att_s,
                                                   const float* __restrict__ att_d,
                                                   float* __restrict__ a_s,
                                                   float* __restrict__ a_d, int n, int C)
{
    int gid = blockIdx.x * BLK + threadIdx.x;
    if (gid >= n * 4) return;
    int hh = gid & 3;
    const float* hr = h + (size_t)gid * C;  // h is [n, 4, C]; gid = node*4+hh
    float s1 = 0.f, s2 = 0.f;
    for (int c = 0; c < C; c++) {
        float v = hr[c];
        s1 += v * att_s[hh * C + c];
        s2 += v * att_d[hh * C + c];
    }
    a_s[gid] = s1;
    a_d[gid] = s2;
}

// ---------------------------------------------------------------------------
// Per (edge, head): e = leaky_relu(a_src[src]+a_dst[dst]); store e; ordered-
// uint atomicMax into menc[dst]. menc pre-memset to 0 (= below -inf in the
// monotonic encoding, so untouched nodes behave like segment_max identity).
// ---------------------------------------------------------------------------
__global__ __launch_bounds__(BLK) void edge_max_kernel(const void* __restrict__ ei_raw,
                                                       const int* __restrict__ flag,
                                                       const float* __restrict__ a_s,
                                                       const float* __restrict__ a_d,
                                                       float* __restrict__ ep,
                                                       unsigned* __restrict__ menc, int E_)
{
    int gid = blockIdx.x * BLK + threadIdx.x;
    if (gid >= E_ * 4) return;
    int is64 = *flag;
    int e = gid >> 2, hh = gid & 3;
    int s, d;
    load_sd(ei_raw, is64, e, E_, s, d);
    float v = a_s[s * 4 + hh] + a_d[d * 4 + hh];
    v = v > 0.f ? v : NEG_SLOPE * v;
    ep[gid] = v;
    unsigned b = __float_as_uint(v);
    unsigned enc = (b & 0x80000000u) ? ~b : (b | 0x80000000u);
    atomicMax(menc + d * 4 + hh, enc);
}

// ---------------------------------------------------------------------------
// Per (edge, head): p = exp(e - m[dst]); store p in-place; atomicAdd to ssum.
// ---------------------------------------------------------------------------
__global__ __launch_bounds__(BLK) void edge_exp_kernel(const void* __restrict__ ei_raw,
                                                       const int* __restrict__ flag,
                                                       float* __restrict__ ep,
                                                       const unsigned* __restrict__ menc,
                                                       float* __restrict__ ssum, int E_)
{
    int gid = blockIdx.x * BLK + threadIdx.x;
    if (gid >= E_ * 4) return;
    int is64 = *flag;
    int e = gid >> 2, hh = gid & 3;
    int s, d;
    load_sd(ei_raw, is64, e, E_, s, d);
    unsigned enc = menc[d * 4 + hh];
    unsigned b = (enc & 0x80000000u) ? (enc ^ 0x80000000u) : ~enc;
    float m = __uint_as_float(b);
    float p = __expf(ep[gid] - m);
    ep[gid] = p;
    atomicAdd(ssum + d * 4 + hh, p);
}

// ---------------------------------------------------------------------------
// Per (edge, feature f in [0, 4*C)): alpha = p/(s[dst]+1e-16);
// agg[dst, f] += h[src, f] * alpha.  Coalesced gather of h rows; atomic
// scatter to agg (zeroed beforehand).
// ---------------------------------------------------------------------------
template <int C>
__global__ __launch_bounds__(BLK) void edge_agg_kernel(const void* __restrict__ ei_raw,
                                                       const int* __restrict__ flag,
                                                       const float* __restrict__ h,
                                                       const float* __restrict__ ep,
                                                       const float* __restrict__ ssum,
                                                       float* __restrict__ agg, int E_)
{
    const int F = 4 * C;
    int gid = blockIdx.x * BLK + threadIdx.x;
    int e = gid / F, f = gid % F;
    if (e >= E_) return;
    int is64 = *flag;
    int s, d;
    load_sd(ei_raw, is64, e, E_, s, d);
    int hh = f / C;
    float alpha = ep[e * 4 + hh] / (ssum[d * 4 + hh] + 1e-16f);
    atomicAdd(agg + (size_t)d * F + f, h[(size_t)s * F + f] * alpha);
}

// ---------------------------------------------------------------------------
// out = elu(agg + bias)   (layers 1 and 2)
// ---------------------------------------------------------------------------
__global__ __launch_bounds__(BLK) void epi_elu_kernel(const float* __restrict__ agg,
                                                      const float* __restrict__ bias,
                                                      float* __restrict__ out, int total,
                                                      int Fmask)
{
    int gid = blockIdx.x * BLK + threadIdx.x;
    if (gid >= total) return;
    float v = agg[gid] + bias[gid & Fmask];
    out[gid] = v > 0.f ? v : (__expf(v) - 1.f);
}

// ---------------------------------------------------------------------------
// out[n, c] = mean over 4 heads of agg[n, h, c] + bias[c]   (layer 3)
// ---------------------------------------------------------------------------
__global__ __launch_bounds__(BLK) void epi_mean_kernel(const float* __restrict__ agg,
                                                       const float* __restrict__ bias,
                                                       float* __restrict__ out, int n)
{
    int gid = blockIdx.x * BLK + threadIdx.x;
    if (gid >= n * 32) return;
    int node = gid >> 5, c = gid & 31;
    const float* ar = agg + (size_t)node * 128;
    float s = (ar[c] + ar[32 + c] + ar[64 + c] + ar[96 + c]) * 0.25f;
    out[gid] = s + bias[c];
}

// ---------------------------------------------------------------------------

extern "C" void kernel_launch(void* const* d_in, const int* in_sizes, int n_in,
                              void* d_out, int out_size, void* d_ws, size_t ws_size,
                              hipStream_t stream)
{
    const float* x   = (const float*)d_in[0];
    const void*  ei  = d_in[1];
    const float* W1  = (const float*)d_in[2];
    const float* as1 = (const float*)d_in[3];
    const float* ad1 = (const float*)d_in[4];
    const float* b1  = (const float*)d_in[5];
    const float* W2  = (const float*)d_in[6];
    const float* as2 = (const float*)d_in[7];
    const float* ad2 = (const float*)d_in[8];
    const float* b2  = (const float*)d_in[9];
    const float* W3  = (const float*)d_in[10];
    const float* as3 = (const float*)d_in[11];
    const float* ad3 = (const float*)d_in[12];
    const float* b3  = (const float*)d_in[13];
    float* out = (float*)d_out;

    const int N_ = in_sizes[0] / 128;
    const int E_ = in_sizes[1] / 2;

    // Workspace carve-up (~100 MB total)
    char* ws = (char*)d_ws;
    size_t off = 0;
    auto alloc = [&](size_t nbytes) -> void* {
        void* p = ws + off;
        off += (nbytes + 255) & ~(size_t)255;
        return p;
    };
    float*    h    = (float*)alloc((size_t)N_ * 128 * 4);  // transformed feats (cur layer)
    float*    agg  = (float*)alloc((size_t)N_ * 128 * 4);  // aggregation accumulator
    float*    x2   = (float*)alloc((size_t)N_ * 32 * 4);   // layer-1 activated output
    float*    x3   = (float*)alloc((size_t)N_ * 128 * 4);  // layer-2 activated output
    float*    ep   = (float*)alloc((size_t)E_ * 4 * 4);    // per-(edge,head) e then p
    float*    asrc = (float*)alloc((size_t)N_ * 4 * 4);
    float*    adst = (float*)alloc((size_t)N_ * 4 * 4);
    unsigned* menc = (unsigned*)alloc((size_t)N_ * 4 * 4);
    float*    ssum = (float*)alloc((size_t)N_ * 4 * 4);
    int*      flag = (int*)alloc(256);

    detect_i64_kernel<<<1, 1, 0, stream>>>(ei, E_, N_, flag);

    const int NH   = N_ * 4;
    const int EH   = E_ * 4;
    const int gEH  = cdiv(EH, BLK);
    const int gNH  = cdiv(NH, BLK);

    // ---------------- Layer 1: 128 -> [4, 8] concat -> 32, then ELU --------
    gemm_kernel<128, 32, 4><<<cdiv((long long)cdiv(N_, 4) * 32, BLK), BLK, 0, stream>>>(
        x, W1, h, N_);
    attn_kernel<<<gNH, BLK, 0, stream>>>(h, as1, ad1, asrc, adst, N_, 8);
    hipMemsetAsync(menc, 0, (size_t)NH * 4, stream);
    edge_max_kernel<<<gEH, BLK, 0, stream>>>(ei, flag, asrc, adst, ep, menc, E_);
    hipMemsetAsync(ssum, 0, (size_t)NH * 4, stream);
    edge_exp_kernel<<<gEH, BLK, 0, stream>>>(ei, flag, ep, menc, ssum, E_);
    hipMemsetAsync(agg, 0, (size_t)N_ * 32 * 4, stream);
    edge_agg_kernel<8><<<cdiv((long long)E_ * 32, BLK), BLK, 0, stream>>>(ei, flag, h, ep,
                                                                          ssum, agg, E_);
    epi_elu_kernel<<<cdiv((long long)N_ * 32, BLK), BLK, 0, stream>>>(agg, b1, x2,
                                                                      N_ * 32, 31);

    // ---------------- Layer 2: 32 -> [4, 32] concat -> 128, then ELU -------
    gemm_kernel<32, 128, 4><<<cdiv((long long)cdiv(N_, 4) * 128, BLK), BLK, 0, stream>>>(
        x2, W2, h, N_);
    attn_kernel<<<gNH, BLK, 0, stream>>>(h, as2, ad2, asrc, adst, N_, 32);
    hipMemsetAsync(menc, 0, (size_t)NH * 4, stream);
    edge_max_kernel<<<gEH, BLK, 0, stream>>>(ei, flag, asrc, adst, ep, menc, E_);
    hipMemsetAsync(ssum, 0, (size_t)NH * 4, stream);
    edge_exp_kernel<<<gEH, BLK, 0, stream>>>(ei, flag, ep, menc, ssum, E_);
    hipMemsetAsync(agg, 0, (size_t)N_ * 128 * 4, stream);
    edge_agg_kernel<32><<<cdiv((long long)E_ * 128, BLK), BLK, 0, stream>>>(ei, flag, h, ep,
                                                                            ssum, agg, E_);
    epi_elu_kernel<<<cdiv((long long)N_ * 128, BLK), BLK, 0, stream>>>(agg, b2, x3,
                                                                       N_ * 128, 127);

    // ---------------- Layer 3: 128 -> [4, 32] mean -> 32 + bias ------------
    gemm_kernel<128, 128, 4><<<cdiv((long long)cdiv(N_, 4) * 128, BLK), BLK, 0, stream>>>(
        x3, W3, h, N_);
    attn_kernel<<<gNH, BLK, 0, stream>>>(h, as3, ad3, asrc, adst, N_, 32);
    hipMemsetAsync(menc, 0, (size_t)NH * 4, stream);
    edge_max_kernel<<<gEH, BLK, 0, stream>>>(ei, flag, asrc, adst, ep, menc, E_);
    hipMemsetAsync(ssum, 0, (size_t)NH * 4, stream);
    edge_exp_kernel<<<gEH, BLK, 0, stream>>>(ei, flag, ep, menc, ssum, E_);
    hipMemsetAsync(agg, 0, (size_t)N_ * 128 * 4, stream);
    edge_agg_kernel<32><<<cdiv((long long)E_ * 128, BLK), BLK, 0, stream>>>(ei, flag, h, ep,
                                                                            ssum, agg, E_);
    epi_mean_kernel<<<cdiv((long long)N_ * 32, BLK), BLK, 0, stream>>>(agg, b3, out, N_);
}

// Round 2
// 797.760 us; speedup vs baseline: 1.7745x; 1.7745x over previous
//
#include <hip/hip_runtime.h>

#define NEG_SLOPE 0.2f

static inline int cdiv(long long a, long long b) { return (int)((a + b - 1) / b); }

// ---------------------------------------------------------------------------
// float4 helpers
// ---------------------------------------------------------------------------
__device__ __forceinline__ float4 f4_add(float4 a, float4 b) {
    return make_float4(a.x + b.x, a.y + b.y, a.z + b.z, a.w + b.w);
}
__device__ __forceinline__ float4 f4_leaky(float4 a) {
    return make_float4(a.x > 0.f ? a.x : NEG_SLOPE * a.x,
                       a.y > 0.f ? a.y : NEG_SLOPE * a.y,
                       a.z > 0.f ? a.z : NEG_SLOPE * a.z,
                       a.w > 0.f ? a.w : NEG_SLOPE * a.w);
}
__device__ __forceinline__ float4 f4_max(float4 a, float4 b) {
    return make_float4(fmaxf(a.x, b.x), fmaxf(a.y, b.y), fmaxf(a.z, b.z),
                       fmaxf(a.w, b.w));
}
__device__ __forceinline__ float4 f4_expsub(float4 e, float4 m) {
    return make_float4(__expf(e.x - m.x), __expf(e.y - m.y), __expf(e.z - m.z),
                       __expf(e.w - m.w));
}

// ---------------------------------------------------------------------------
// int64-vs-int32 edge_index probe (see Round-1 notes: all-in-range as int64
// <=> the buffer really is int64).
// ---------------------------------------------------------------------------
__global__ void detect_i64_kernel(const void* ei_raw, int E_, int n, int* flag)
{
    if (blockIdx.x == 0 && threadIdx.x == 0) {
        const long long* e64 = (const long long*)ei_raw;
        int cnt = E_ < 512 ? E_ : 512;
        int ok = 1;
        for (int i = 0; i < cnt; i++) {
            long long v = e64[i];
            if (v < 0 || v >= n) { ok = 0; break; }
        }
        *flag = ok;
    }
}

__device__ __forceinline__ void load_sd(const void* ei_raw, int is64, int e, int E_,
                                        int& s, int& d)
{
    if (is64) {
        const long long* p = (const long long*)ei_raw;
        s = (int)p[e];
        d = (int)p[E_ + e];
    } else {
        const int* p = (const int*)ei_raw;
        s = p[e];
        d = p[E_ + e];
    }
}

// ---------------------------------------------------------------------------
// CSR build: histogram of dst, exclusive scan, scatter src into sorted order.
// ---------------------------------------------------------------------------
__global__ __launch_bounds__(256) void hist_kernel(const void* __restrict__ ei_raw,
                                                   const int* __restrict__ flag,
                                                   int* __restrict__ deg, int E_)
{
    int e = blockIdx.x * 256 + threadIdx.x;
    if (e >= E_) return;
    int is64 = *flag;
    int s, d;
    load_sd(ei_raw, is64, e, E_, s, d);
    atomicAdd(deg + d, 1);
}

__device__ __forceinline__ int wave_incl_scan(int v)
{
    int lane = threadIdx.x & 63;
#pragma unroll
    for (int off = 1; off < 64; off <<= 1) {
        int t = __shfl_up(v, off);
        if (lane >= off) v += t;
    }
    return v;
}

// Single-block exclusive scan of deg[n] -> start[n+1]; cursor gets a copy.
__global__ __launch_bounds__(1024) void scan_kernel(const int* __restrict__ deg,
                                                    int* __restrict__ start,
                                                    int* __restrict__ cursor, int n)
{
    __shared__ int wsum[16];
    __shared__ int carry_sh;
    if (threadIdx.x == 0) carry_sh = 0;
    __syncthreads();
    int wid = threadIdx.x >> 6, lane = threadIdx.x & 63;
    int nIter = (n + 1023) / 1024;
    for (int it = 0; it < nIter; it++) {
        int i = it * 1024 + threadIdx.x;
        int v = (i < n) ? deg[i] : 0;
        int incl = wave_incl_scan(v);
        if (lane == 63) wsum[wid] = incl;
        __syncthreads();
        if (wid == 0) {
            int w = (lane < 16) ? wsum[lane] : 0;
            w = wave_incl_scan(w);
            if (lane < 16) wsum[lane] = w;
        }
        __syncthreads();
        int waveoff = (wid > 0) ? wsum[wid - 1] : 0;
        incl += waveoff;
        int carry = carry_sh;
        int excl = incl - v + carry;
        if (i < n) { start[i] = excl; cursor[i] = excl; }
        __syncthreads();
        if (threadIdx.x == 1023) carry_sh = carry + incl;
        __syncthreads();
    }
    if (threadIdx.x == 0) start[n] = carry_sh;
}

__global__ __launch_bounds__(256) void scatter_kernel(const void* __restrict__ ei_raw,
                                                      const int* __restrict__ flag,
                                                      int* __restrict__ cursor,
                                                      int* __restrict__ sorted_src, int E_)
{
    int e = blockIdx.x * 256 + threadIdx.x;
    if (e >= E_) return;
    int is64 = *flag;
    int s, d;
    load_sd(ei_raw, is64, e, E_, s, d);
    int pos = atomicAdd(cursor + d, 1);
    sorted_src[pos] = s;
}

// ---------------------------------------------------------------------------
// h = x @ W   (W cached in LDS; one output column x NPT nodes per thread)
// ---------------------------------------------------------------------------
template <int INC, int OUTC, int NPT>
__global__ __launch_bounds__(256) void gemm_kernel(const float* __restrict__ x,
                                                   const float* __restrict__ W,
                                                   float* __restrict__ h, int n)
{
    __shared__ float Wl[INC * OUTC];
    for (int i = threadIdx.x; i < INC * OUTC; i += 256) Wl[i] = W[i];
    __syncthreads();

    int gid = blockIdx.x * 256 + threadIdx.x;
    int j = gid % OUTC;
    int g = gid / OUTC;
    int n0 = g * NPT;
    if (n0 >= n) return;

    float acc[NPT];
#pragma unroll
    for (int t = 0; t < NPT; t++) acc[t] = 0.f;

    const float* xr = x + (size_t)n0 * INC;
#pragma unroll 4
    for (int k = 0; k < INC; k++) {
        float w = Wl[k * OUTC + j];
#pragma unroll
        for (int t = 0; t < NPT; t++) acc[t] += xr[(size_t)t * INC + k] * w;
    }
#pragma unroll
    for (int t = 0; t < NPT; t++) {
        if (n0 + t < n) h[(size_t)(n0 + t) * OUTC + j] = acc[t];
    }
}

// ---------------------------------------------------------------------------
// a_src[n,4], a_dst[n,4] dot-products. One thread per (node, head).
// ---------------------------------------------------------------------------
__global__ __launch_bounds__(256) void attn_kernel(const float* __restrict__ h,
                                                   const float* __restrict__ att_s,
                                                   const float* __restrict__ att_d,
                                                   float* __restrict__ a_s,
                                                   float* __restrict__ a_d, int n, int C)
{
    int gid = blockIdx.x * 256 + threadIdx.x;
    if (gid >= n * 4) return;
    int hh = gid & 3;
    const float* hr = h + (size_t)gid * C;
    float s1 = 0.f, s2 = 0.f;
    for (int c = 0; c < C; c++) {
        float v = hr[c];
        s1 += v * att_s[hh * C + c];
        s2 += v * att_d[hh * C + c];
    }
    a_s[gid] = s1;
    a_d[gid] = s2;
}

// ---------------------------------------------------------------------------
// Per-node softmax over the CSR edge list: one wave per dst node, all 4
// heads at once (a_src rows are float4). Three passes (max, sumexp, write
// alpha) re-gathering a_src — 16 B/edge/pass, L2-hot. No atomics.
// ---------------------------------------------------------------------------
__global__ __launch_bounds__(256) void node_softmax_kernel(
    const int* __restrict__ start, const int* __restrict__ sorted_src,
    const float* __restrict__ a_s, const float* __restrict__ a_d,
    float* __restrict__ alpha, int n)
{
    int wid = threadIdx.x >> 6;
    int lane = threadIdx.x & 63;
    int node = blockIdx.x * 4 + wid;
    if (node >= n) return;
    int s0 = start[node], s1 = start[node + 1];
    if (s0 == s1) return;

    const float4* as4 = (const float4*)a_s;
    float4 ad = ((const float4*)a_d)[node];

    // pass 1: max
    float4 mx = make_float4(-INFINITY, -INFINITY, -INFINITY, -INFINITY);
    for (int i = s0 + lane; i < s1; i += 64) {
        int s = sorted_src[i];
        float4 e = f4_leaky(f4_add(as4[s], ad));
        mx = f4_max(mx, e);
    }
#pragma unroll
    for (int off = 32; off; off >>= 1) {
        mx.x = fmaxf(mx.x, __shfl_xor(mx.x, off));
        mx.y = fmaxf(mx.y, __shfl_xor(mx.y, off));
        mx.z = fmaxf(mx.z, __shfl_xor(mx.z, off));
        mx.w = fmaxf(mx.w, __shfl_xor(mx.w, off));
    }

    // pass 2: sum of exp
    float4 sm = make_float4(0.f, 0.f, 0.f, 0.f);
    for (int i = s0 + lane; i < s1; i += 64) {
        int s = sorted_src[i];
        float4 e = f4_leaky(f4_add(as4[s], ad));
        sm = f4_add(sm, f4_expsub(e, mx));
    }
#pragma unroll
    for (int off = 32; off; off >>= 1) {
        sm.x += __shfl_xor(sm.x, off);
        sm.y += __shfl_xor(sm.y, off);
        sm.z += __shfl_xor(sm.z, off);
        sm.w += __shfl_xor(sm.w, off);
    }
    float4 inv = make_float4(1.f / (sm.x + 1e-16f), 1.f / (sm.y + 1e-16f),
                             1.f / (sm.z + 1e-16f), 1.f / (sm.w + 1e-16f));

    // pass 3: write alpha (float4 per edge)
    float4* al4 = (float4*)alpha;
    for (int i = s0 + lane; i < s1; i += 64) {
        int s = sorted_src[i];
        float4 e = f4_leaky(f4_add(as4[s], ad));
        float4 p = f4_expsub(e, mx);
        al4[i] = make_float4(p.x * inv.x, p.y * inv.y, p.z * inv.z, p.w * inv.w);
    }
}

// ---------------------------------------------------------------------------
// Per-node aggregation, F = 128 (layers 2 and 3). 128 threads per node,
// 2 nodes per 256-block. Coalesced 512 B gathers of h[src]; each output
// element written exactly once. MODE 0: +bias, ELU (layer 2). MODE 1:
// head-mean, +bias (layer 3).
// ---------------------------------------------------------------------------
template <int MODE>
__global__ __launch_bounds__(256) void node_agg128_kernel(
    const int* __restrict__ start, const int* __restrict__ sorted_src,
    const float* __restrict__ h, const float* __restrict__ alpha,
    const float* __restrict__ bias, float* __restrict__ out, int n)
{
    int local = threadIdx.x >> 7;  // 0 or 1
    int f = threadIdx.x & 127;
    int node = blockIdx.x * 2 + local;
    bool active = node < n;
    int s0 = 0, s1 = 0;
    if (active) { s0 = start[node]; s1 = start[node + 1]; }
    int hh = f >> 5;

    float acc = 0.f;
    int i = s0;
    for (; i + 1 < s1; i += 2) {
        int sA = sorted_src[i];
        int sB = sorted_src[i + 1];
        float aA = alpha[i * 4 + hh];
        float aB = alpha[(i + 1) * 4 + hh];
        acc += h[(size_t)sA * 128 + f] * aA;
        acc += h[(size_t)sB * 128 + f] * aB;
    }
    if (i < s1) {
        int sA = sorted_src[i];
        acc += h[(size_t)sA * 128 + f] * alpha[i * 4 + hh];
    }

    if (MODE == 0) {
        if (active) {
            float v = acc + bias[f];
            out[(size_t)node * 128 + f] = v > 0.f ? v : (__expf(v) - 1.f);
        }
    } else {
        __shared__ float sh[256];
        sh[threadIdx.x] = acc;
        __syncthreads();
        if (f < 32 && active) {
            int b = local * 128;
            float sum = sh[b + f] + sh[b + 32 + f] + sh[b + 64 + f] + sh[b + 96 + f];
            out[(size_t)node * 32 + f] = 0.25f * sum + bias[f];
        }
    }
}

// ---------------------------------------------------------------------------
// Per-node aggregation, F = 32 (layer 1). 32 threads per node, 8 nodes per
// block. Fused bias + ELU.
// ---------------------------------------------------------------------------
__global__ __launch_bounds__(256) void node_agg32_kernel(
    const int* __restrict__ start, const int* __restrict__ sorted_src,
    const float* __restrict__ h, const float* __restrict__ alpha,
    const float* __restrict__ bias, float* __restrict__ out, int n)
{
    int local = threadIdx.x >> 5;  // 0..7
    int f = threadIdx.x & 31;
    int node = blockIdx.x * 8 + local;
    if (node >= n) return;
    int s0 = start[node], s1 = start[node + 1];
    int hh = f >> 3;

    float acc = 0.f;
    int i = s0;
    for (; i + 1 < s1; i += 2) {
        int sA = sorted_src[i];
        int sB = sorted_src[i + 1];
        float aA = alpha[i * 4 + hh];
        float aB = alpha[(i + 1) * 4 + hh];
        acc += h[(size_t)sA * 32 + f] * aA;
        acc += h[(size_t)sB * 32 + f] * aB;
    }
    if (i < s1) {
        int sA = sorted_src[i];
        acc += h[(size_t)sA * 32 + f] * alpha[i * 4 + hh];
    }
    float v = acc + bias[f];
    out[(size_t)node * 32 + f] = v > 0.f ? v : (__expf(v) - 1.f);
}

// ---------------------------------------------------------------------------

extern "C" void kernel_launch(void* const* d_in, const int* in_sizes, int n_in,
                              void* d_out, int out_size, void* d_ws, size_t ws_size,
                              hipStream_t stream)
{
    const float* x   = (const float*)d_in[0];
    const void*  ei  = d_in[1];
    const float* W1  = (const float*)d_in[2];
    const float* as1 = (const float*)d_in[3];
    const float* ad1 = (const float*)d_in[4];
    const float* b1  = (const float*)d_in[5];
    const float* W2  = (const float*)d_in[6];
    const float* as2 = (const float*)d_in[7];
    const float* ad2 = (const float*)d_in[8];
    const float* b2  = (const float*)d_in[9];
    const float* W3  = (const float*)d_in[10];
    const float* as3 = (const float*)d_in[11];
    const float* ad3 = (const float*)d_in[12];
    const float* b3  = (const float*)d_in[13];
    float* out = (float*)d_out;

    const int N_ = in_sizes[0] / 128;
    const int E_ = in_sizes[1] / 2;

    // Workspace carve-up (~76 MB)
    char* ws = (char*)d_ws;
    size_t off = 0;
    auto alloc = [&](size_t nbytes) -> void* {
        void* p = ws + off;
        off += (nbytes + 255) & ~(size_t)255;
        return p;
    };
    float* h          = (float*)alloc((size_t)N_ * 128 * 4);
    float* x2         = (float*)alloc((size_t)N_ * 32 * 4);
    float* x3         = (float*)alloc((size_t)N_ * 128 * 4);
    float* alpha      = (float*)alloc((size_t)E_ * 4 * 4);
    float* asrc       = (float*)alloc((size_t)N_ * 4 * 4);
    float* adst       = (float*)alloc((size_t)N_ * 4 * 4);
    int*   deg        = (int*)alloc((size_t)N_ * 4);
    int*   start      = (int*)alloc((size_t)(N_ + 1) * 4);
    int*   cursor     = (int*)alloc((size_t)N_ * 4);
    int*   sorted_src = (int*)alloc((size_t)E_ * 4);
    int*   flag       = (int*)alloc(256);

    const int gE  = cdiv(E_, 256);
    const int gNH = cdiv(N_ * 4, 256);
    const int gW4 = cdiv(N_, 4);   // node_softmax: 4 nodes/block
    const int gN2 = cdiv(N_, 2);   // agg128: 2 nodes/block
    const int gN8 = cdiv(N_, 8);   // agg32: 8 nodes/block

    // ---- CSR build (once; shared by all 3 layers) ----
    detect_i64_kernel<<<1, 1, 0, stream>>>(ei, E_, N_, flag);
    hipMemsetAsync(deg, 0, (size_t)N_ * 4, stream);
    hist_kernel<<<gE, 256, 0, stream>>>(ei, flag, deg, E_);
    scan_kernel<<<1, 1024, 0, stream>>>(deg, start, cursor, N_);
    scatter_kernel<<<gE, 256, 0, stream>>>(ei, flag, cursor, sorted_src, E_);

    // ---- Layer 1: 128 -> [4,8] concat=32, ELU ----
    gemm_kernel<128, 32, 4><<<cdiv((long long)cdiv(N_, 4) * 32, 256), 256, 0, stream>>>(
        x, W1, h, N_);
    attn_kernel<<<gNH, 256, 0, stream>>>(h, as1, ad1, asrc, adst, N_, 8);
    node_softmax_kernel<<<gW4, 256, 0, stream>>>(start, sorted_src, asrc, adst, alpha, N_);
    node_agg32_kernel<<<gN8, 256, 0, stream>>>(start, sorted_src, h, alpha, b1, x2, N_);

    // ---- Layer 2: 32 -> [4,32] concat=128, ELU ----
    gemm_kernel<32, 128, 4><<<cdiv((long long)cdiv(N_, 4) * 128, 256), 256, 0, stream>>>(
        x2, W2, h, N_);
    attn_kernel<<<gNH, 256, 0, stream>>>(h, as2, ad2, asrc, adst, N_, 32);
    node_softmax_kernel<<<gW4, 256, 0, stream>>>(start, sorted_src, asrc, adst, alpha, N_);
    node_agg128_kernel<0><<<gN2, 256, 0, stream>>>(start, sorted_src, h, alpha, b2, x3, N_);

    // ---- Layer 3: 128 -> [4,32] mean=32 ----
    gemm_kernel<128, 128, 4><<<cdiv((long long)cdiv(N_, 4) * 128, 256), 256, 0, stream>>>(
        x3, W3, h, N_);
    attn_kernel<<<gNH, 256, 0, stream>>>(h, as3, ad3, asrc, adst, N_, 32);
    node_softmax_kernel<<<gW4, 256, 0, stream>>>(start, sorted_src, asrc, adst, alpha, N_);
    node_agg128_kernel<1><<<gN2, 256, 0, stream>>>(start, sorted_src, h, alpha, b3, out, N_);
}

// Round 3
// 644.812 us; speedup vs baseline: 2.1954x; 1.2372x over previous
//
#include <hip/hip_runtime.h>

#define NEG_SLOPE 0.2f

static inline int cdiv(long long a, long long b) { return (int)((a + b - 1) / b); }

// ---------------------------------------------------------------------------
// float4 helpers
// ---------------------------------------------------------------------------
__device__ __forceinline__ float4 f4_add(float4 a, float4 b) {
    return make_float4(a.x + b.x, a.y + b.y, a.z + b.z, a.w + b.w);
}
__device__ __forceinline__ float4 f4_leaky(float4 a) {
    return make_float4(a.x > 0.f ? a.x : NEG_SLOPE * a.x,
                       a.y > 0.f ? a.y : NEG_SLOPE * a.y,
                       a.z > 0.f ? a.z : NEG_SLOPE * a.z,
                       a.w > 0.f ? a.w : NEG_SLOPE * a.w);
}
__device__ __forceinline__ float4 f4_max(float4 a, float4 b) {
    return make_float4(fmaxf(a.x, b.x), fmaxf(a.y, b.y), fmaxf(a.z, b.z),
                       fmaxf(a.w, b.w));
}
__device__ __forceinline__ float4 f4_expsub(float4 e, float4 m) {
    return make_float4(__expf(e.x - m.x), __expf(e.y - m.y), __expf(e.z - m.z),
                       __expf(e.w - m.w));
}

// ---------------------------------------------------------------------------
// int64-vs-int32 edge_index probe (all-in-range as int64 <=> really int64).
// ---------------------------------------------------------------------------
__global__ void detect_i64_kernel(const void* ei_raw, int E_, int n, int* flag)
{
    if (blockIdx.x == 0 && threadIdx.x == 0) {
        const long long* e64 = (const long long*)ei_raw;
        int cnt = E_ < 512 ? E_ : 512;
        int ok = 1;
        for (int i = 0; i < cnt; i++) {
            long long v = e64[i];
            if (v < 0 || v >= n) { ok = 0; break; }
        }
        *flag = ok;
    }
}

__device__ __forceinline__ void load_sd(const void* ei_raw, int is64, int e, int E_,
                                        int& s, int& d)
{
    if (is64) {
        const long long* p = (const long long*)ei_raw;
        s = (int)p[e];
        d = (int)p[E_ + e];
    } else {
        const int* p = (const int*)ei_raw;
        s = p[e];
        d = p[E_ + e];
    }
}

// ---------------------------------------------------------------------------
// CSR build: histogram of dst, exclusive scan, scatter src into sorted order.
// ---------------------------------------------------------------------------
__global__ __launch_bounds__(256) void hist_kernel(const void* __restrict__ ei_raw,
                                                   const int* __restrict__ flag,
                                                   int* __restrict__ deg, int E_)
{
    int e = blockIdx.x * 256 + threadIdx.x;
    if (e >= E_) return;
    int is64 = *flag;
    int s, d;
    load_sd(ei_raw, is64, e, E_, s, d);
    atomicAdd(deg + d, 1);
}

__device__ __forceinline__ int wave_incl_scan(int v)
{
    int lane = threadIdx.x & 63;
#pragma unroll
    for (int off = 1; off < 64; off <<= 1) {
        int t = __shfl_up(v, off);
        if (lane >= off) v += t;
    }
    return v;
}

// Single-block exclusive scan of deg[n] -> start[n+1]; cursor gets a copy.
__global__ __launch_bounds__(1024) void scan_kernel(const int* __restrict__ deg,
                                                    int* __restrict__ start,
                                                    int* __restrict__ cursor, int n)
{
    __shared__ int wsum[16];
    __shared__ int carry_sh;
    if (threadIdx.x == 0) carry_sh = 0;
    __syncthreads();
    int wid = threadIdx.x >> 6, lane = threadIdx.x & 63;
    int nIter = (n + 1023) / 1024;
    for (int it = 0; it < nIter; it++) {
        int i = it * 1024 + threadIdx.x;
        int v = (i < n) ? deg[i] : 0;
        int incl = wave_incl_scan(v);
        if (lane == 63) wsum[wid] = incl;
        __syncthreads();
        if (wid == 0) {
            int w = (lane < 16) ? wsum[lane] : 0;
            w = wave_incl_scan(w);
            if (lane < 16) wsum[lane] = w;
        }
        __syncthreads();
        int waveoff = (wid > 0) ? wsum[wid - 1] : 0;
        incl += waveoff;
        int carry = carry_sh;
        int excl = incl - v + carry;
        if (i < n) { start[i] = excl; cursor[i] = excl; }
        __syncthreads();
        if (threadIdx.x == 1023) carry_sh = carry + incl;
        __syncthreads();
    }
    if (threadIdx.x == 0) start[n] = carry_sh;
}

__global__ __launch_bounds__(256) void scatter_kernel(const void* __restrict__ ei_raw,
                                                      const int* __restrict__ flag,
                                                      int* __restrict__ cursor,
                                                      int* __restrict__ sorted_src, int E_)
{
    int e = blockIdx.x * 256 + threadIdx.x;
    if (e >= E_) return;
    int is64 = *flag;
    int s, d;
    load_sd(ei_raw, is64, e, E_, s, d);
    int pos = atomicAdd(cursor + d, 1);
    sorted_src[pos] = s;
}

// ---------------------------------------------------------------------------
// Tiled fp32 GEMM: h[n, NOUT] = x[n, K] @ W[K, NOUT].
// Block = 256 threads. Each thread owns NPT=8 nodes x 4 cols (float4 acc).
// K staged in chunks of KC=32: Xs transposed [k][node] (+4 pad keeps float4
// alignment; nodegroup reads are 2-way bank aliased = free), Ws natural.
// Inner k-step: 3 ds_read_b128 + 32 v_fmac for 64 FLOP.
// LDS: NOUT=128 -> 25 KB (6 blk/CU); NOUT=32 -> 37 KB (4 blk/CU).
// ---------------------------------------------------------------------------
template <int K, int NOUT>
__global__ __launch_bounds__(256) void gemm_tiled_kernel(const float* __restrict__ x,
                                                         const float* __restrict__ W,
                                                         float* __restrict__ h, int n)
{
    constexpr int NPT  = 8;
    constexpr int COLQ = NOUT / 4;        // col quads (8 or 32)
    constexpr int NG   = 256 / COLQ;      // node groups per block
    constexpr int MT   = NG * NPT;        // nodes per block (256 or 64)
    constexpr int KC   = 32;              // k chunk
    constexpr int XLD  = MT + 4;          // padded leading dim (float4-aligned)

    __shared__ float Xs[KC][XLD];
    __shared__ float Ws[KC][NOUT];

    const int tid  = threadIdx.x;
    const int colq = tid % COLQ;
    const int ng   = tid / COLQ;
    const int nb   = blockIdx.x * MT;
    const int n0   = ng * NPT;            // this thread's first node within tile

    float4 acc[NPT];
#pragma unroll
    for (int t = 0; t < NPT; t++) acc[t] = make_float4(0.f, 0.f, 0.f, 0.f);

    for (int kc = 0; kc < K; kc += KC) {
        // ---- stage X chunk (transposed) ----
#pragma unroll
        for (int q = tid; q < MT * (KC / 4); q += 256) {
            int node = q / (KC / 4);
            int kq   = q % (KC / 4);
            int gn   = nb + node;
            float4 v = make_float4(0.f, 0.f, 0.f, 0.f);
            if (gn < n) v = *(const float4*)(x + (size_t)gn * K + kc + kq * 4);
            Xs[kq * 4 + 0][node] = v.x;
            Xs[kq * 4 + 1][node] = v.y;
            Xs[kq * 4 + 2][node] = v.z;
            Xs[kq * 4 + 3][node] = v.w;
        }
        // ---- stage W chunk (contiguous rows kc..kc+KC) ----
        const float4* Wg = (const float4*)(W + (size_t)kc * NOUT);
#pragma unroll
        for (int q = tid; q < KC * NOUT / 4; q += 256) {
            ((float4*)&Ws[0][0])[q] = Wg[q];
        }
        __syncthreads();

        // ---- compute ----
#pragma unroll
        for (int k = 0; k < KC; k++) {
            float4 w4 = *(const float4*)&Ws[k][colq * 4];
#pragma unroll
            for (int t = 0; t < NPT; t += 4) {
                float4 xv = *(const float4*)&Xs[k][n0 + t];
                acc[t + 0].x += xv.x * w4.x; acc[t + 0].y += xv.x * w4.y;
                acc[t + 0].z += xv.x * w4.z; acc[t + 0].w += xv.x * w4.w;
                acc[t + 1].x += xv.y * w4.x; acc[t + 1].y += xv.y * w4.y;
                acc[t + 1].z += xv.y * w4.z; acc[t + 1].w += xv.y * w4.w;
                acc[t + 2].x += xv.z * w4.x; acc[t + 2].y += xv.z * w4.y;
                acc[t + 2].z += xv.z * w4.z; acc[t + 2].w += xv.z * w4.w;
                acc[t + 3].x += xv.w * w4.x; acc[t + 3].y += xv.w * w4.y;
                acc[t + 3].z += xv.w * w4.z; acc[t + 3].w += xv.w * w4.w;
            }
        }
        __syncthreads();
    }

#pragma unroll
    for (int t = 0; t < NPT; t++) {
        int gn = nb + n0 + t;
        if (gn < n) *(float4*)(h + (size_t)gn * NOUT + colq * 4) = acc[t];
    }
}

// ---------------------------------------------------------------------------
// a_src[n,4], a_dst[n,4] dot-products. One thread per (node, head); float4.
// ---------------------------------------------------------------------------
__global__ __launch_bounds__(256) void attn_kernel(const float* __restrict__ h,
                                                   const float* __restrict__ att_s,
                                                   const float* __restrict__ att_d,
                                                   float* __restrict__ a_s,
                                                   float* __restrict__ a_d, int n, int C)
{
    int gid = blockIdx.x * 256 + threadIdx.x;
    if (gid >= n * 4) return;
    int hh = gid & 3;
    const float4* hr  = (const float4*)(h + (size_t)gid * C);
    const float4* as4 = (const float4*)(att_s + hh * C);
    const float4* ad4 = (const float4*)(att_d + hh * C);
    float s1 = 0.f, s2 = 0.f;
    int C4 = C >> 2;
    for (int c = 0; c < C4; c++) {
        float4 v = hr[c];
        float4 a = as4[c];
        float4 b = ad4[c];
        s1 += v.x * a.x + v.y * a.y + v.z * a.z + v.w * a.w;
        s2 += v.x * b.x + v.y * b.y + v.z * b.z + v.w * b.w;
    }
    a_s[gid] = s1;
    a_d[gid] = s2;
}

// ---------------------------------------------------------------------------
// Per-node softmax over CSR edge list: one wave per dst node, 4 heads at once.
// ---------------------------------------------------------------------------
__global__ __launch_bounds__(256) void node_softmax_kernel(
    const int* __restrict__ start, const int* __restrict__ sorted_src,
    const float* __restrict__ a_s, const float* __restrict__ a_d,
    float* __restrict__ alpha, int n)
{
    int wid = threadIdx.x >> 6;
    int lane = threadIdx.x & 63;
    int node = blockIdx.x * 4 + wid;
    if (node >= n) return;
    int s0 = start[node], s1 = start[node + 1];
    if (s0 == s1) return;

    const float4* as4 = (const float4*)a_s;
    float4 ad = ((const float4*)a_d)[node];

    float4 mx = make_float4(-INFINITY, -INFINITY, -INFINITY, -INFINITY);
    for (int i = s0 + lane; i < s1; i += 64) {
        int s = sorted_src[i];
        float4 e = f4_leaky(f4_add(as4[s], ad));
        mx = f4_max(mx, e);
    }
#pragma unroll
    for (int off = 32; off; off >>= 1) {
        mx.x = fmaxf(mx.x, __shfl_xor(mx.x, off));
        mx.y = fmaxf(mx.y, __shfl_xor(mx.y, off));
        mx.z = fmaxf(mx.z, __shfl_xor(mx.z, off));
        mx.w = fmaxf(mx.w, __shfl_xor(mx.w, off));
    }

    float4 sm = make_float4(0.f, 0.f, 0.f, 0.f);
    for (int i = s0 + lane; i < s1; i += 64) {
        int s = sorted_src[i];
        float4 e = f4_leaky(f4_add(as4[s], ad));
        sm = f4_add(sm, f4_expsub(e, mx));
    }
#pragma unroll
    for (int off = 32; off; off >>= 1) {
        sm.x += __shfl_xor(sm.x, off);
        sm.y += __shfl_xor(sm.y, off);
        sm.z += __shfl_xor(sm.z, off);
        sm.w += __shfl_xor(sm.w, off);
    }
    float4 inv = make_float4(1.f / (sm.x + 1e-16f), 1.f / (sm.y + 1e-16f),
                             1.f / (sm.z + 1e-16f), 1.f / (sm.w + 1e-16f));

    float4* al4 = (float4*)alpha;
    for (int i = s0 + lane; i < s1; i += 64) {
        int s = sorted_src[i];
        float4 e = f4_leaky(f4_add(as4[s], ad));
        float4 p = f4_expsub(e, mx);
        al4[i] = make_float4(p.x * inv.x, p.y * inv.y, p.z * inv.z, p.w * inv.w);
    }
}

// ---------------------------------------------------------------------------
// Per-node aggregation, F = 128 (layers 2/3). 128 threads/node, 2 nodes/block.
// MODE 0: +bias, ELU. MODE 1: head-mean, +bias.
// ---------------------------------------------------------------------------
template <int MODE>
__global__ __launch_bounds__(256) void node_agg128_kernel(
    const int* __restrict__ start, const int* __restrict__ sorted_src,
    const float* __restrict__ h, const float* __restrict__ alpha,
    const float* __restrict__ bias, float* __restrict__ out, int n)
{
    int local = threadIdx.x >> 7;
    int f = threadIdx.x & 127;
    int node = blockIdx.x * 2 + local;
    bool active = node < n;
    int s0 = 0, s1 = 0;
    if (active) { s0 = start[node]; s1 = start[node + 1]; }
    int hh = f >> 5;

    float acc = 0.f;
    int i = s0;
    for (; i + 1 < s1; i += 2) {
        int sA = sorted_src[i];
        int sB = sorted_src[i + 1];
        float aA = alpha[i * 4 + hh];
        float aB = alpha[(i + 1) * 4 + hh];
        acc += h[(size_t)sA * 128 + f] * aA;
        acc += h[(size_t)sB * 128 + f] * aB;
    }
    if (i < s1) {
        int sA = sorted_src[i];
        acc += h[(size_t)sA * 128 + f] * alpha[i * 4 + hh];
    }

    if (MODE == 0) {
        if (active) {
            float v = acc + bias[f];
            out[(size_t)node * 128 + f] = v > 0.f ? v : (__expf(v) - 1.f);
        }
    } else {
        __shared__ float sh[256];
        sh[threadIdx.x] = acc;
        __syncthreads();
        if (f < 32 && active) {
            int b = local * 128;
            float sum = sh[b + f] + sh[b + 32 + f] + sh[b + 64 + f] + sh[b + 96 + f];
            out[(size_t)node * 32 + f] = 0.25f * sum + bias[f];
        }
    }
}

// ---------------------------------------------------------------------------
// Per-node aggregation, F = 32 (layer 1). 32 threads/node, 8 nodes/block.
// ---------------------------------------------------------------------------
__global__ __launch_bounds__(256) void node_agg32_kernel(
    const int* __restrict__ start, const int* __restrict__ sorted_src,
    const float* __restrict__ h, const float* __restrict__ alpha,
    const float* __restrict__ bias, float* __restrict__ out, int n)
{
    int local = threadIdx.x >> 5;
    int f = threadIdx.x & 31;
    int node = blockIdx.x * 8 + local;
    if (node >= n) return;
    int s0 = start[node], s1 = start[node + 1];
    int hh = f >> 3;

    float acc = 0.f;
    int i = s0;
    for (; i + 1 < s1; i += 2) {
        int sA = sorted_src[i];
        int sB = sorted_src[i + 1];
        float aA = alpha[i * 4 + hh];
        float aB = alpha[(i + 1) * 4 + hh];
        acc += h[(size_t)sA * 32 + f] * aA;
        acc += h[(size_t)sB * 32 + f] * aB;
    }
    if (i < s1) {
        int sA = sorted_src[i];
        acc += h[(size_t)sA * 32 + f] * alpha[i * 4 + hh];
    }
    float v = acc + bias[f];
    out[(size_t)node * 32 + f] = v > 0.f ? v : (__expf(v) - 1.f);
}

// ---------------------------------------------------------------------------

extern "C" void kernel_launch(void* const* d_in, const int* in_sizes, int n_in,
                              void* d_out, int out_size, void* d_ws, size_t ws_size,
                              hipStream_t stream)
{
    const float* x   = (const float*)d_in[0];
    const void*  ei  = d_in[1];
    const float* W1  = (const float*)d_in[2];
    const float* as1 = (const float*)d_in[3];
    const float* ad1 = (const float*)d_in[4];
    const float* b1  = (const float*)d_in[5];
    const float* W2  = (const float*)d_in[6];
    const float* as2 = (const float*)d_in[7];
    const float* ad2 = (const float*)d_in[8];
    const float* b2  = (const float*)d_in[9];
    const float* W3  = (const float*)d_in[10];
    const float* as3 = (const float*)d_in[11];
    const float* ad3 = (const float*)d_in[12];
    const float* b3  = (const float*)d_in[13];
    float* out = (float*)d_out;

    const int N_ = in_sizes[0] / 128;
    const int E_ = in_sizes[1] / 2;

    char* ws = (char*)d_ws;
    size_t off = 0;
    auto alloc = [&](size_t nbytes) -> void* {
        void* p = ws + off;
        off += (nbytes + 255) & ~(size_t)255;
        return p;
    };
    float* h          = (float*)alloc((size_t)N_ * 128 * 4);
    float* x2         = (float*)alloc((size_t)N_ * 32 * 4);
    float* x3         = (float*)alloc((size_t)N_ * 128 * 4);
    float* alpha      = (float*)alloc((size_t)E_ * 4 * 4);
    float* asrc       = (float*)alloc((size_t)N_ * 4 * 4);
    float* adst       = (float*)alloc((size_t)N_ * 4 * 4);
    int*   deg        = (int*)alloc((size_t)N_ * 4);
    int*   start      = (int*)alloc((size_t)(N_ + 1) * 4);
    int*   cursor     = (int*)alloc((size_t)N_ * 4);
    int*   sorted_src = (int*)alloc((size_t)E_ * 4);
    int*   flag       = (int*)alloc(256);

    const int gE  = cdiv(E_, 256);
    const int gNH = cdiv(N_ * 4, 256);
    const int gW4 = cdiv(N_, 4);
    const int gN2 = cdiv(N_, 2);
    const int gN8 = cdiv(N_, 8);

    // ---- CSR build (once; shared by all 3 layers) ----
    detect_i64_kernel<<<1, 1, 0, stream>>>(ei, E_, N_, flag);
    hipMemsetAsync(deg, 0, (size_t)N_ * 4, stream);
    hist_kernel<<<gE, 256, 0, stream>>>(ei, flag, deg, E_);
    scan_kernel<<<1, 1024, 0, stream>>>(deg, start, cursor, N_);
    scatter_kernel<<<gE, 256, 0, stream>>>(ei, flag, cursor, sorted_src, E_);

    // ---- Layer 1: 128 -> [4,8] concat=32, ELU ----
    gemm_tiled_kernel<128, 32><<<cdiv(N_, 256), 256, 0, stream>>>(x, W1, h, N_);
    attn_kernel<<<gNH, 256, 0, stream>>>(h, as1, ad1, asrc, adst, N_, 8);
    node_softmax_kernel<<<gW4, 256, 0, stream>>>(start, sorted_src, asrc, adst, alpha, N_);
    node_agg32_kernel<<<gN8, 256, 0, stream>>>(start, sorted_src, h, alpha, b1, x2, N_);

    // ---- Layer 2: 32 -> [4,32] concat=128, ELU ----
    gemm_tiled_kernel<32, 128><<<cdiv(N_, 64), 256, 0, stream>>>(x2, W2, h, N_);
    attn_kernel<<<gNH, 256, 0, stream>>>(h, as2, ad2, asrc, adst, N_, 32);
    node_softmax_kernel<<<gW4, 256, 0, stream>>>(start, sorted_src, asrc, adst, alpha, N_);
    node_agg128_kernel<0><<<gN2, 256, 0, stream>>>(start, sorted_src, h, alpha, b2, x3, N_);

    // ---- Layer 3: 128 -> [4,32] mean=32 ----
    gemm_tiled_kernel<128, 128><<<cdiv(N_, 64), 256, 0, stream>>>(x3, W3, h, N_);
    attn_kernel<<<gNH, 256, 0, stream>>>(h, as3, ad3, asrc, adst, N_, 32);
    node_softmax_kernel<<<gW4, 256, 0, stream>>>(start, sorted_src, asrc, adst, alpha, N_);
    node_agg128_kernel<1><<<gN2, 256, 0, stream>>>(start, sorted_src, h, alpha, b3, out, N_);
}

// Round 4
// 591.409 us; speedup vs baseline: 2.3936x; 1.0903x over previous
//
#include <hip/hip_runtime.h>

#define NEG_SLOPE 0.2f

static inline int cdiv(long long a, long long b) { return (int)((a + b - 1) / b); }

// ---------------------------------------------------------------------------
// float4 helpers
// ---------------------------------------------------------------------------
__device__ __forceinline__ float4 f4_add(float4 a, float4 b) {
    return make_float4(a.x + b.x, a.y + b.y, a.z + b.z, a.w + b.w);
}
__device__ __forceinline__ float4 f4_leaky(float4 a) {
    return make_float4(a.x > 0.f ? a.x : NEG_SLOPE * a.x,
                       a.y > 0.f ? a.y : NEG_SLOPE * a.y,
                       a.z > 0.f ? a.z : NEG_SLOPE * a.z,
                       a.w > 0.f ? a.w : NEG_SLOPE * a.w);
}
__device__ __forceinline__ float4 f4_max(float4 a, float4 b) {
    return make_float4(fmaxf(a.x, b.x), fmaxf(a.y, b.y), fmaxf(a.z, b.z),
                       fmaxf(a.w, b.w));
}
__device__ __forceinline__ float4 f4_expsub(float4 e, float4 m) {
    return make_float4(__expf(e.x - m.x), __expf(e.y - m.y), __expf(e.z - m.z),
                       __expf(e.w - m.w));
}

// ---------------------------------------------------------------------------
// int64-vs-int32 edge_index probe (all-in-range as int64 <=> really int64).
// ---------------------------------------------------------------------------
__global__ void detect_i64_kernel(const void* ei_raw, int E_, int n, int* flag)
{
    if (blockIdx.x == 0 && threadIdx.x == 0) {
        const long long* e64 = (const long long*)ei_raw;
        int cnt = E_ < 512 ? E_ : 512;
        int ok = 1;
        for (int i = 0; i < cnt; i++) {
            long long v = e64[i];
            if (v < 0 || v >= n) { ok = 0; break; }
        }
        *flag = ok;
    }
}

__device__ __forceinline__ void load_sd(const void* ei_raw, int is64, int e, int E_,
                                        int& s, int& d)
{
    if (is64) {
        const long long* p = (const long long*)ei_raw;
        s = (int)p[e];
        d = (int)p[E_ + e];
    } else {
        const int* p = (const int*)ei_raw;
        s = p[e];
        d = p[E_ + e];
    }
}

// ---------------------------------------------------------------------------
// CSR build: histogram of dst, exclusive scan, scatter src into sorted order.
// ---------------------------------------------------------------------------
__global__ __launch_bounds__(256) void hist_kernel(const void* __restrict__ ei_raw,
                                                   const int* __restrict__ flag,
                                                   int* __restrict__ deg, int E_)
{
    int e = blockIdx.x * 256 + threadIdx.x;
    if (e >= E_) return;
    int is64 = *flag;
    int s, d;
    load_sd(ei_raw, is64, e, E_, s, d);
    atomicAdd(deg + d, 1);
}

__device__ __forceinline__ int wave_incl_scan(int v)
{
    int lane = threadIdx.x & 63;
#pragma unroll
    for (int off = 1; off < 64; off <<= 1) {
        int t = __shfl_up(v, off);
        if (lane >= off) v += t;
    }
    return v;
}

// Single-block exclusive scan of deg[n] -> start[n+1]; cursor gets a copy.
__global__ __launch_bounds__(1024) void scan_kernel(const int* __restrict__ deg,
                                                    int* __restrict__ start,
                                                    int* __restrict__ cursor, int n)
{
    __shared__ int wsum[16];
    __shared__ int carry_sh;
    if (threadIdx.x == 0) carry_sh = 0;
    __syncthreads();
    int wid = threadIdx.x >> 6, lane = threadIdx.x & 63;
    int nIter = (n + 1023) / 1024;
    for (int it = 0; it < nIter; it++) {
        int i = it * 1024 + threadIdx.x;
        int v = (i < n) ? deg[i] : 0;
        int incl = wave_incl_scan(v);
        if (lane == 63) wsum[wid] = incl;
        __syncthreads();
        if (wid == 0) {
            int w = (lane < 16) ? wsum[lane] : 0;
            w = wave_incl_scan(w);
            if (lane < 16) wsum[lane] = w;
        }
        __syncthreads();
        int waveoff = (wid > 0) ? wsum[wid - 1] : 0;
        incl += waveoff;
        int carry = carry_sh;
        int excl = incl - v + carry;
        if (i < n) { start[i] = excl; cursor[i] = excl; }
        __syncthreads();
        if (threadIdx.x == 1023) carry_sh = carry + incl;
        __syncthreads();
    }
    if (threadIdx.x == 0) start[n] = carry_sh;
}

__global__ __launch_bounds__(256) void scatter_kernel(const void* __restrict__ ei_raw,
                                                      const int* __restrict__ flag,
                                                      int* __restrict__ cursor,
                                                      int* __restrict__ sorted_src, int E_)
{
    int e = blockIdx.x * 256 + threadIdx.x;
    if (e >= E_) return;
    int is64 = *flag;
    int s, d;
    load_sd(ei_raw, is64, e, E_, s, d);
    int pos = atomicAdd(cursor + d, 1);
    sorted_src[pos] = s;
}

// ---------------------------------------------------------------------------
// Tiled fp32 GEMM: h[n, NOUT] = x[n, K] @ W[K, NOUT].  (See Round-3 notes.)
// ---------------------------------------------------------------------------
template <int K, int NOUT>
__global__ __launch_bounds__(256) void gemm_tiled_kernel(const float* __restrict__ x,
                                                         const float* __restrict__ W,
                                                         float* __restrict__ h, int n)
{
    constexpr int NPT  = 8;
    constexpr int COLQ = NOUT / 4;
    constexpr int NG   = 256 / COLQ;
    constexpr int MT   = NG * NPT;
    constexpr int KC   = 32;
    constexpr int XLD  = MT + 4;

    __shared__ float Xs[KC][XLD];
    __shared__ float Ws[KC][NOUT];

    const int tid  = threadIdx.x;
    const int colq = tid % COLQ;
    const int ng   = tid / COLQ;
    const int nb   = blockIdx.x * MT;
    const int n0   = ng * NPT;

    float4 acc[NPT];
#pragma unroll
    for (int t = 0; t < NPT; t++) acc[t] = make_float4(0.f, 0.f, 0.f, 0.f);

    for (int kc = 0; kc < K; kc += KC) {
#pragma unroll
        for (int q = tid; q < MT * (KC / 4); q += 256) {
            int node = q / (KC / 4);
            int kq   = q % (KC / 4);
            int gn   = nb + node;
            float4 v = make_float4(0.f, 0.f, 0.f, 0.f);
            if (gn < n) v = *(const float4*)(x + (size_t)gn * K + kc + kq * 4);
            Xs[kq * 4 + 0][node] = v.x;
            Xs[kq * 4 + 1][node] = v.y;
            Xs[kq * 4 + 2][node] = v.z;
            Xs[kq * 4 + 3][node] = v.w;
        }
        const float4* Wg = (const float4*)(W + (size_t)kc * NOUT);
#pragma unroll
        for (int q = tid; q < KC * NOUT / 4; q += 256) {
            ((float4*)&Ws[0][0])[q] = Wg[q];
        }
        __syncthreads();

#pragma unroll
        for (int k = 0; k < KC; k++) {
            float4 w4 = *(const float4*)&Ws[k][colq * 4];
#pragma unroll
            for (int t = 0; t < NPT; t += 4) {
                float4 xv = *(const float4*)&Xs[k][n0 + t];
                acc[t + 0].x += xv.x * w4.x; acc[t + 0].y += xv.x * w4.y;
                acc[t + 0].z += xv.x * w4.z; acc[t + 0].w += xv.x * w4.w;
                acc[t + 1].x += xv.y * w4.x; acc[t + 1].y += xv.y * w4.y;
                acc[t + 1].z += xv.y * w4.z; acc[t + 1].w += xv.y * w4.w;
                acc[t + 2].x += xv.z * w4.x; acc[t + 2].y += xv.z * w4.y;
                acc[t + 2].z += xv.z * w4.z; acc[t + 2].w += xv.z * w4.w;
                acc[t + 3].x += xv.w * w4.x; acc[t + 3].y += xv.w * w4.y;
                acc[t + 3].z += xv.w * w4.z; acc[t + 3].w += xv.w * w4.w;
            }
        }
        __syncthreads();
    }

#pragma unroll
    for (int t = 0; t < NPT; t++) {
        int gn = nb + n0 + t;
        if (gn < n) *(float4*)(h + (size_t)gn * NOUT + colq * 4) = acc[t];
    }
}

// ---------------------------------------------------------------------------
// a_src[n,4], a_dst[n,4] dot-products. One thread per (node, head); float4.
// ---------------------------------------------------------------------------
__global__ __launch_bounds__(256) void attn_kernel(const float* __restrict__ h,
                                                   const float* __restrict__ att_s,
                                                   const float* __restrict__ att_d,
                                                   float* __restrict__ a_s,
                                                   float* __restrict__ a_d, int n, int C)
{
    int gid = blockIdx.x * 256 + threadIdx.x;
    if (gid >= n * 4) return;
    int hh = gid & 3;
    const float4* hr  = (const float4*)(h + (size_t)gid * C);
    const float4* as4 = (const float4*)(att_s + hh * C);
    const float4* ad4 = (const float4*)(att_d + hh * C);
    float s1 = 0.f, s2 = 0.f;
    int C4 = C >> 2;
    for (int c = 0; c < C4; c++) {
        float4 v = hr[c];
        float4 a = as4[c];
        float4 b = ad4[c];
        s1 += v.x * a.x + v.y * a.y + v.z * a.z + v.w * a.w;
        s2 += v.x * b.x + v.y * b.y + v.z * b.z + v.w * b.w;
    }
    a_s[gid] = s1;
    a_d[gid] = s2;
}

// ---------------------------------------------------------------------------
// Per-node softmax over CSR edge list: one wave per dst node, 4 heads at once.
// Pass 1 does the ONLY random gather (a_s[src]) and caches e in the alpha
// buffer; passes 2-3 stream it sequentially.
// ---------------------------------------------------------------------------
__global__ __launch_bounds__(256) void node_softmax_kernel(
    const int* __restrict__ start, const int* __restrict__ sorted_src,
    const float* __restrict__ a_s, const float* __restrict__ a_d,
    float* __restrict__ alpha, int n)
{
    int wid = threadIdx.x >> 6;
    int lane = threadIdx.x & 63;
    int node = blockIdx.x * 4 + wid;
    if (node >= n) return;
    int s0 = start[node], s1 = start[node + 1];
    if (s0 == s1) return;

    const float4* as4 = (const float4*)a_s;
    float4 ad = ((const float4*)a_d)[node];
    float4* al4 = (float4*)alpha;

    // pass 1: gather, compute e, cache to alpha, running max
    float4 mx = make_float4(-INFINITY, -INFINITY, -INFINITY, -INFINITY);
    for (int i = s0 + lane; i < s1; i += 64) {
        int s = sorted_src[i];
        float4 e = f4_leaky(f4_add(as4[s], ad));
        al4[i] = e;
        mx = f4_max(mx, e);
    }
#pragma unroll
    for (int off = 32; off; off >>= 1) {
        mx.x = fmaxf(mx.x, __shfl_xor(mx.x, off));
        mx.y = fmaxf(mx.y, __shfl_xor(mx.y, off));
        mx.z = fmaxf(mx.z, __shfl_xor(mx.z, off));
        mx.w = fmaxf(mx.w, __shfl_xor(mx.w, off));
    }

    // pass 2: sequential re-read, sum of exp
    float4 sm = make_float4(0.f, 0.f, 0.f, 0.f);
    for (int i = s0 + lane; i < s1; i += 64) {
        sm = f4_add(sm, f4_expsub(al4[i], mx));
    }
#pragma unroll
    for (int off = 32; off; off >>= 1) {
        sm.x += __shfl_xor(sm.x, off);
        sm.y += __shfl_xor(sm.y, off);
        sm.z += __shfl_xor(sm.z, off);
        sm.w += __shfl_xor(sm.w, off);
    }
    float4 inv = make_float4(1.f / (sm.x + 1e-16f), 1.f / (sm.y + 1e-16f),
                             1.f / (sm.z + 1e-16f), 1.f / (sm.w + 1e-16f));

    // pass 3: normalize in place
    for (int i = s0 + lane; i < s1; i += 64) {
        float4 p = f4_expsub(al4[i], mx);
        al4[i] = make_float4(p.x * inv.x, p.y * inv.y, p.z * inv.z, p.w * inv.w);
    }
}

// ---------------------------------------------------------------------------
// Per-node aggregation, F = 128 (layers 2/3). 128 threads/node, 2 nodes/block.
// Software-pipelined: 8-edge windows -> 8 independent h-row gathers in
// flight per wave (latency-bound random gather; see Round-4 notes).
// MODE 0: +bias, ELU. MODE 1: head-mean, +bias.
// ---------------------------------------------------------------------------
template <int MODE>
__global__ __launch_bounds__(256) void node_agg128_kernel(
    const int* __restrict__ start, const int* __restrict__ sorted_src,
    const float* __restrict__ h, const float* __restrict__ alpha,
    const float* __restrict__ bias, float* __restrict__ out, int n)
{
    int local = threadIdx.x >> 7;
    int f = threadIdx.x & 127;
    int node = blockIdx.x * 2 + local;
    bool active = node < n;
    int s0 = 0, s1 = 0;
    if (active) { s0 = start[node]; s1 = start[node + 1]; }
    int hh = f >> 5;
    const float* __restrict__ hf = h + f;

    float acc = 0.f;
    int i = s0;
    for (; i + 8 <= s1; i += 8) {
        int   sj[8];
        float aj[8];
#pragma unroll
        for (int j = 0; j < 8; j++) sj[j] = sorted_src[i + j];
#pragma unroll
        for (int j = 0; j < 8; j++) aj[j] = alpha[(i + j) * 4 + hh];
        float vj[8];
#pragma unroll
        for (int j = 0; j < 8; j++) vj[j] = hf[(size_t)sj[j] * 128];
#pragma unroll
        for (int j = 0; j < 8; j++) acc += vj[j] * aj[j];
    }
    for (; i < s1; i++) {
        acc += hf[(size_t)sorted_src[i] * 128] * alpha[i * 4 + hh];
    }

    if (MODE == 0) {
        if (active) {
            float v = acc + bias[f];
            out[(size_t)node * 128 + f] = v > 0.f ? v : (__expf(v) - 1.f);
        }
    } else {
        __shared__ float sh[256];
        sh[threadIdx.x] = acc;
        __syncthreads();
        if (f < 32 && active) {
            int b = local * 128;
            float sum = sh[b + f] + sh[b + 32 + f] + sh[b + 64 + f] + sh[b + 96 + f];
            out[(size_t)node * 32 + f] = 0.25f * sum + bias[f];
        }
    }
}

// ---------------------------------------------------------------------------
// Per-node aggregation, F = 32 (layer 1). 32 threads/node, 8 nodes/block.
// Same 8-deep pipelining.
// ---------------------------------------------------------------------------
__global__ __launch_bounds__(256) void node_agg32_kernel(
    const int* __restrict__ start, const int* __restrict__ sorted_src,
    const float* __restrict__ h, const float* __restrict__ alpha,
    const float* __restrict__ bias, float* __restrict__ out, int n)
{
    int local = threadIdx.x >> 5;
    int f = threadIdx.x & 31;
    int node = blockIdx.x * 8 + local;
    if (node >= n) return;
    int s0 = start[node], s1 = start[node + 1];
    int hh = f >> 3;
    const float* __restrict__ hf = h + f;

    float acc = 0.f;
    int i = s0;
    for (; i + 8 <= s1; i += 8) {
        int   sj[8];
        float aj[8];
#pragma unroll
        for (int j = 0; j < 8; j++) sj[j] = sorted_src[i + j];
#pragma unroll
        for (int j = 0; j < 8; j++) aj[j] = alpha[(i + j) * 4 + hh];
        float vj[8];
#pragma unroll
        for (int j = 0; j < 8; j++) vj[j] = hf[(size_t)sj[j] * 32];
#pragma unroll
        for (int j = 0; j < 8; j++) acc += vj[j] * aj[j];
    }
    for (; i < s1; i++) {
        acc += hf[(size_t)sorted_src[i] * 32] * alpha[i * 4 + hh];
    }
    float v = acc + bias[f];
    out[(size_t)node * 32 + f] = v > 0.f ? v : (__expf(v) - 1.f);
}

// ---------------------------------------------------------------------------

extern "C" void kernel_launch(void* const* d_in, const int* in_sizes, int n_in,
                              void* d_out, int out_size, void* d_ws, size_t ws_size,
                              hipStream_t stream)
{
    const float* x   = (const float*)d_in[0];
    const void*  ei  = d_in[1];
    const float* W1  = (const float*)d_in[2];
    const float* as1 = (const float*)d_in[3];
    const float* ad1 = (const float*)d_in[4];
    const float* b1  = (const float*)d_in[5];
    const float* W2  = (const float*)d_in[6];
    const float* as2 = (const float*)d_in[7];
    const float* ad2 = (const float*)d_in[8];
    const float* b2  = (const float*)d_in[9];
    const float* W3  = (const float*)d_in[10];
    const float* as3 = (const float*)d_in[11];
    const float* ad3 = (const float*)d_in[12];
    const float* b3  = (const float*)d_in[13];
    float* out = (float*)d_out;

    const int N_ = in_sizes[0] / 128;
    const int E_ = in_sizes[1] / 2;

    char* ws = (char*)d_ws;
    size_t off = 0;
    auto alloc = [&](size_t nbytes) -> void* {
        void* p = ws + off;
        off += (nbytes + 255) & ~(size_t)255;
        return p;
    };
    float* h          = (float*)alloc((size_t)N_ * 128 * 4);
    float* x2         = (float*)alloc((size_t)N_ * 32 * 4);
    float* x3         = (float*)alloc((size_t)N_ * 128 * 4);
    float* alpha      = (float*)alloc((size_t)E_ * 4 * 4);
    float* asrc       = (float*)alloc((size_t)N_ * 4 * 4);
    float* adst       = (float*)alloc((size_t)N_ * 4 * 4);
    int*   deg        = (int*)alloc((size_t)N_ * 4);
    int*   start      = (int*)alloc((size_t)(N_ + 1) * 4);
    int*   cursor     = (int*)alloc((size_t)N_ * 4);
    int*   sorted_src = (int*)alloc((size_t)E_ * 4);
    int*   flag       = (int*)alloc(256);

    const int gE  = cdiv(E_, 256);
    const int gNH = cdiv(N_ * 4, 256);
    const int gW4 = cdiv(N_, 4);
    const int gN2 = cdiv(N_, 2);
    const int gN8 = cdiv(N_, 8);

    // ---- CSR build (once; shared by all 3 layers) ----
    detect_i64_kernel<<<1, 1, 0, stream>>>(ei, E_, N_, flag);
    hipMemsetAsync(deg, 0, (size_t)N_ * 4, stream);
    hist_kernel<<<gE, 256, 0, stream>>>(ei, flag, deg, E_);
    scan_kernel<<<1, 1024, 0, stream>>>(deg, start, cursor, N_);
    scatter_kernel<<<gE, 256, 0, stream>>>(ei, flag, cursor, sorted_src, E_);

    // ---- Layer 1: 128 -> [4,8] concat=32, ELU ----
    gemm_tiled_kernel<128, 32><<<cdiv(N_, 256), 256, 0, stream>>>(x, W1, h, N_);
    attn_kernel<<<gNH, 256, 0, stream>>>(h, as1, ad1, asrc, adst, N_, 8);
    node_softmax_kernel<<<gW4, 256, 0, stream>>>(start, sorted_src, asrc, adst, alpha, N_);
    node_agg32_kernel<<<gN8, 256, 0, stream>>>(start, sorted_src, h, alpha, b1, x2, N_);

    // ---- Layer 2: 32 -> [4,32] concat=128, ELU ----
    gemm_tiled_kernel<32, 128><<<cdiv(N_, 64), 256, 0, stream>>>(x2, W2, h, N_);
    attn_kernel<<<gNH, 256, 0, stream>>>(h, as2, ad2, asrc, adst, N_, 32);
    node_softmax_kernel<<<gW4, 256, 0, stream>>>(start, sorted_src, asrc, adst, alpha, N_);
    node_agg128_kernel<0><<<gN2, 256, 0, stream>>>(start, sorted_src, h, alpha, b2, x3, N_);

    // ---- Layer 3: 128 -> [4,32] mean=32 ----
    gemm_tiled_kernel<128, 128><<<cdiv(N_, 64), 256, 0, stream>>>(x3, W3, h, N_);
    attn_kernel<<<gNH, 256, 0, stream>>>(h, as3, ad3, asrc, adst, N_, 32);
    node_softmax_kernel<<<gW4, 256, 0, stream>>>(start, sorted_src, asrc, adst, alpha, N_);
    node_agg128_kernel<1><<<gN2, 256, 0, stream>>>(start, sorted_src, h, alpha, b3, out, N_);
}

// Round 5
// 497.568 us; speedup vs baseline: 2.8450x; 1.1886x over previous
//
#include <hip/hip_runtime.h>

#define NEG_SLOPE 0.2f

static inline int cdiv(long long a, long long b) { return (int)((a + b - 1) / b); }

// ---------------------------------------------------------------------------
// float4 helpers
// ---------------------------------------------------------------------------
__device__ __forceinline__ float4 f4_add(float4 a, float4 b) {
    return make_float4(a.x + b.x, a.y + b.y, a.z + b.z, a.w + b.w);
}
__device__ __forceinline__ float4 f4_leaky(float4 a) {
    return make_float4(a.x > 0.f ? a.x : NEG_SLOPE * a.x,
                       a.y > 0.f ? a.y : NEG_SLOPE * a.y,
                       a.z > 0.f ? a.z : NEG_SLOPE * a.z,
                       a.w > 0.f ? a.w : NEG_SLOPE * a.w);
}
__device__ __forceinline__ float4 f4_max(float4 a, float4 b) {
    return make_float4(fmaxf(a.x, b.x), fmaxf(a.y, b.y), fmaxf(a.z, b.z),
                       fmaxf(a.w, b.w));
}
__device__ __forceinline__ float4 f4_expsub(float4 e, float4 m) {
    return make_float4(__expf(e.x - m.x), __expf(e.y - m.y), __expf(e.z - m.z),
                       __expf(e.w - m.w));
}

// ---------------------------------------------------------------------------
// int64-vs-int32 edge_index probe (all-in-range as int64 <=> really int64).
// ---------------------------------------------------------------------------
__global__ void detect_i64_kernel(const void* ei_raw, int E_, int n, int* flag)
{
    if (blockIdx.x == 0 && threadIdx.x == 0) {
        const long long* e64 = (const long long*)ei_raw;
        int cnt = E_ < 512 ? E_ : 512;
        int ok = 1;
        for (int i = 0; i < cnt; i++) {
            long long v = e64[i];
            if (v < 0 || v >= n) { ok = 0; break; }
        }
        *flag = ok;
    }
}

__device__ __forceinline__ void load_sd(const void* ei_raw, int is64, int e, int E_,
                                        int& s, int& d)
{
    if (is64) {
        const long long* p = (const long long*)ei_raw;
        s = (int)p[e];
        d = (int)p[E_ + e];
    } else {
        const int* p = (const int*)ei_raw;
        s = p[e];
        d = p[E_ + e];
    }
}

// ---------------------------------------------------------------------------
// CSR build: histogram, 3-kernel parallel scan, scatter.
// ---------------------------------------------------------------------------
__global__ __launch_bounds__(256) void hist_kernel(const void* __restrict__ ei_raw,
                                                   const int* __restrict__ flag,
                                                   int* __restrict__ deg, int E_)
{
    int e = blockIdx.x * 256 + threadIdx.x;
    if (e >= E_) return;
    int is64 = *flag;
    int s, d;
    load_sd(ei_raw, is64, e, E_, s, d);
    atomicAdd(deg + d, 1);
}

__device__ __forceinline__ int wave_incl_scan(int v)
{
    int lane = threadIdx.x & 63;
#pragma unroll
    for (int off = 1; off < 64; off <<= 1) {
        int t = __shfl_up(v, off);
        if (lane >= off) v += t;
    }
    return v;
}

// Per-block exclusive scan of 1024 elems; block total to bsum.
__global__ __launch_bounds__(1024) void scan_part_kernel(const int* __restrict__ deg,
                                                         int* __restrict__ start,
                                                         int* __restrict__ bsum, int n)
{
    __shared__ int wsum[16];
    int i = blockIdx.x * 1024 + threadIdx.x;
    int wid = threadIdx.x >> 6, lane = threadIdx.x & 63;
    int v = (i < n) ? deg[i] : 0;
    int incl = wave_incl_scan(v);
    if (lane == 63) wsum[wid] = incl;
    __syncthreads();
    if (wid == 0) {
        int w = (lane < 16) ? wsum[lane] : 0;
        w = wave_incl_scan(w);
        if (lane < 16) wsum[lane] = w;
    }
    __syncthreads();
    int excl = incl - v + (wid ? wsum[wid - 1] : 0);
    if (i < n) start[i] = excl;
    if (threadIdx.x == 1023) bsum[blockIdx.x] = wsum[15];
}

// Single block: exclusive scan of block sums (nb <= 1024).
__global__ __launch_bounds__(1024) void scan_bsum_kernel(int* __restrict__ bsum, int nb)
{
    __shared__ int sh[1024];
    int t = threadIdx.x;
    sh[t] = (t < nb) ? bsum[t] : 0;
    __syncthreads();
    for (int off = 1; off < 1024; off <<= 1) {
        int val = (t >= off) ? sh[t - off] : 0;
        __syncthreads();
        sh[t] += val;
        __syncthreads();
    }
    if (t < nb) bsum[t] = t ? sh[t - 1] : 0;
}

__global__ __launch_bounds__(1024) void scan_add_kernel(const int* __restrict__ deg,
                                                        const int* __restrict__ boffs,
                                                        int* __restrict__ start,
                                                        int* __restrict__ cursor, int n)
{
    int i = blockIdx.x * 1024 + threadIdx.x;
    if (i >= n) return;
    int v = start[i] + boffs[blockIdx.x];
    start[i] = v;
    cursor[i] = v;
    if (i == n - 1) start[n] = v + deg[i];
}

__global__ __launch_bounds__(256) void scatter_kernel(const void* __restrict__ ei_raw,
                                                      const int* __restrict__ flag,
                                                      int* __restrict__ cursor,
                                                      int* __restrict__ sorted_src, int E_)
{
    int e = blockIdx.x * 256 + threadIdx.x;
    if (e >= E_) return;
    int is64 = *flag;
    int s, d;
    load_sd(ei_raw, is64, e, E_, s, d);
    int pos = atomicAdd(cursor + d, 1);
    sorted_src[pos] = s;
}

// ---------------------------------------------------------------------------
// Tiled fp32 GEMM with FUSED attention-coefficient epilogue:
//   h[n, NOUT] = x[n, K] @ W[K, NOUT]
//   a_s[n,4]   = sum_c h[n,hd,c] * att_s[hd,c]   (likewise a_d)
// Thread owns 4 cols (colq) x NPT=8 nodes. Heads = 4, C = NOUT/4,
// R = C/4 lanes share one (node, head) -> shfl_xor tree reduction.
// att f4 index == colq (since head*C/4 + colq%R == colq). See Round-5 notes.
// ---------------------------------------------------------------------------
template <int K, int NOUT>
__global__ __launch_bounds__(256) void gemm_attn_kernel(
    const float* __restrict__ x, const float* __restrict__ W,
    const float* __restrict__ att_s, const float* __restrict__ att_d,
    float* __restrict__ h, float* __restrict__ a_s, float* __restrict__ a_d, int n)
{
    constexpr int NPT  = 8;
    constexpr int COLQ = NOUT / 4;
    constexpr int NG   = 256 / COLQ;
    constexpr int MT   = NG * NPT;
    constexpr int KC   = 32;
    constexpr int XLD  = MT + 4;
    constexpr int R    = COLQ / 4;   // lanes per (node, head) group

    __shared__ float Xs[KC][XLD];
    __shared__ float Ws[KC][NOUT];

    const int tid  = threadIdx.x;
    const int colq = tid % COLQ;
    const int ng   = tid / COLQ;
    const int nb   = blockIdx.x * MT;
    const int n0   = ng * NPT;

    float4 acc[NPT];
#pragma unroll
    for (int t = 0; t < NPT; t++) acc[t] = make_float4(0.f, 0.f, 0.f, 0.f);

    for (int kc = 0; kc < K; kc += KC) {
#pragma unroll
        for (int q = tid; q < MT * (KC / 4); q += 256) {
            int node = q / (KC / 4);
            int kq   = q % (KC / 4);
            int gn   = nb + node;
            float4 v = make_float4(0.f, 0.f, 0.f, 0.f);
            if (gn < n) v = *(const float4*)(x + (size_t)gn * K + kc + kq * 4);
            Xs[kq * 4 + 0][node] = v.x;
            Xs[kq * 4 + 1][node] = v.y;
            Xs[kq * 4 + 2][node] = v.z;
            Xs[kq * 4 + 3][node] = v.w;
        }
        const float4* Wg = (const float4*)(W + (size_t)kc * NOUT);
#pragma unroll
        for (int q = tid; q < KC * NOUT / 4; q += 256) {
            ((float4*)&Ws[0][0])[q] = Wg[q];
        }
        __syncthreads();

#pragma unroll
        for (int k = 0; k < KC; k++) {
            float4 w4 = *(const float4*)&Ws[k][colq * 4];
#pragma unroll
            for (int t = 0; t < NPT; t += 4) {
                float4 xv = *(const float4*)&Xs[k][n0 + t];
                acc[t + 0].x += xv.x * w4.x; acc[t + 0].y += xv.x * w4.y;
                acc[t + 0].z += xv.x * w4.z; acc[t + 0].w += xv.x * w4.w;
                acc[t + 1].x += xv.y * w4.x; acc[t + 1].y += xv.y * w4.y;
                acc[t + 1].z += xv.y * w4.z; acc[t + 1].w += xv.y * w4.w;
                acc[t + 2].x += xv.z * w4.x; acc[t + 2].y += xv.z * w4.y;
                acc[t + 2].z += xv.z * w4.z; acc[t + 2].w += xv.z * w4.w;
                acc[t + 3].x += xv.w * w4.x; acc[t + 3].y += xv.w * w4.y;
                acc[t + 3].z += xv.w * w4.z; acc[t + 3].w += xv.w * w4.w;
            }
        }
        __syncthreads();
    }

    // ---- h store ----
#pragma unroll
    for (int t = 0; t < NPT; t++) {
        int gn = nb + n0 + t;
        if (gn < n) *(float4*)(h + (size_t)gn * NOUT + colq * 4) = acc[t];
    }

    // ---- fused attention coefficients ----
    const float4 avs = ((const float4*)att_s)[colq];
    const float4 avd = ((const float4*)att_d)[colq];
    const int head = colq / R;
    float ps[NPT], pd[NPT];
#pragma unroll
    for (int t = 0; t < NPT; t++) {
        ps[t] = acc[t].x * avs.x + acc[t].y * avs.y + acc[t].z * avs.z + acc[t].w * avs.w;
        pd[t] = acc[t].x * avd.x + acc[t].y * avd.y + acc[t].z * avd.z + acc[t].w * avd.w;
    }
#pragma unroll
    for (int off = R >> 1; off; off >>= 1) {
#pragma unroll
        for (int t = 0; t < NPT; t++) {
            ps[t] += __shfl_xor(ps[t], off);
            pd[t] += __shfl_xor(pd[t], off);
        }
    }
    if (colq % R == 0) {
#pragma unroll
        for (int t = 0; t < NPT; t++) {
            int gn = nb + n0 + t;
            if (gn < n) {
                a_s[gn * 4 + head] = ps[t];
                a_d[gn * 4 + head] = pd[t];
            }
        }
    }
}

// ---------------------------------------------------------------------------
// Per-node softmax, one wave per dst node, 4 heads at once.
// Fast path deg<=64: one edge per lane, everything in registers — single
// random gather + single alpha write. (P(deg>64) ~ 0 at mean 16, sd 4.)
// ---------------------------------------------------------------------------
__global__ __launch_bounds__(256) void node_softmax_kernel(
    const int* __restrict__ start, const int* __restrict__ sorted_src,
    const float* __restrict__ a_s, const float* __restrict__ a_d,
    float* __restrict__ alpha, int n)
{
    int wid = threadIdx.x >> 6;
    int lane = threadIdx.x & 63;
    int node = blockIdx.x * 4 + wid;
    if (node >= n) return;
    int s0 = start[node], s1 = start[node + 1];
    int deg = s1 - s0;
    if (deg == 0) return;

    const float4* as4 = (const float4*)a_s;
    float4 ad = ((const float4*)a_d)[node];
    float4* al4 = (float4*)alpha;

    if (deg <= 64) {
        bool valid = lane < deg;
        int s = valid ? sorted_src[s0 + lane] : 0;
        float4 e = valid ? f4_leaky(f4_add(as4[s], ad))
                         : make_float4(-INFINITY, -INFINITY, -INFINITY, -INFINITY);
        float4 mx = e;
#pragma unroll
        for (int off = 32; off; off >>= 1) {
            mx.x = fmaxf(mx.x, __shfl_xor(mx.x, off));
            mx.y = fmaxf(mx.y, __shfl_xor(mx.y, off));
            mx.z = fmaxf(mx.z, __shfl_xor(mx.z, off));
            mx.w = fmaxf(mx.w, __shfl_xor(mx.w, off));
        }
        float4 p = valid ? f4_expsub(e, mx) : make_float4(0.f, 0.f, 0.f, 0.f);
        float4 sm = p;
#pragma unroll
        for (int off = 32; off; off >>= 1) {
            sm.x += __shfl_xor(sm.x, off);
            sm.y += __shfl_xor(sm.y, off);
            sm.z += __shfl_xor(sm.z, off);
            sm.w += __shfl_xor(sm.w, off);
        }
        if (valid) {
            al4[s0 + lane] = make_float4(p.x / (sm.x + 1e-16f), p.y / (sm.y + 1e-16f),
                                         p.z / (sm.z + 1e-16f), p.w / (sm.w + 1e-16f));
        }
        return;
    }

    // fallback: 3-pass with e cached in alpha
    float4 mx = make_float4(-INFINITY, -INFINITY, -INFINITY, -INFINITY);
    for (int i = s0 + lane; i < s1; i += 64) {
        int s = sorted_src[i];
        float4 e = f4_leaky(f4_add(as4[s], ad));
        al4[i] = e;
        mx = f4_max(mx, e);
    }
#pragma unroll
    for (int off = 32; off; off >>= 1) {
        mx.x = fmaxf(mx.x, __shfl_xor(mx.x, off));
        mx.y = fmaxf(mx.y, __shfl_xor(mx.y, off));
        mx.z = fmaxf(mx.z, __shfl_xor(mx.z, off));
        mx.w = fmaxf(mx.w, __shfl_xor(mx.w, off));
    }
    float4 sm = make_float4(0.f, 0.f, 0.f, 0.f);
    for (int i = s0 + lane; i < s1; i += 64) {
        sm = f4_add(sm, f4_expsub(al4[i], mx));
    }
#pragma unroll
    for (int off = 32; off; off >>= 1) {
        sm.x += __shfl_xor(sm.x, off);
        sm.y += __shfl_xor(sm.y, off);
        sm.z += __shfl_xor(sm.z, off);
        sm.w += __shfl_xor(sm.w, off);
    }
    float4 inv = make_float4(1.f / (sm.x + 1e-16f), 1.f / (sm.y + 1e-16f),
                             1.f / (sm.z + 1e-16f), 1.f / (sm.w + 1e-16f));
    for (int i = s0 + lane; i < s1; i += 64) {
        float4 p = f4_expsub(al4[i], mx);
        al4[i] = make_float4(p.x * inv.x, p.y * inv.y, p.z * inv.z, p.w * inv.w);
    }
}

// ---------------------------------------------------------------------------
// Per-node aggregation, F = 128 (layers 2/3). 32 threads/node (float4 per
// thread), 8 nodes/block, 8-edge software pipeline (8 x 16 B gathers in
// flight per thread). MODE 0: +bias, ELU. MODE 1: head-mean, +bias.
// ---------------------------------------------------------------------------
template <int MODE>
__global__ __launch_bounds__(256) void node_agg128_kernel(
    const int* __restrict__ start, const int* __restrict__ sorted_src,
    const float* __restrict__ h, const float* __restrict__ alpha,
    const float* __restrict__ bias, float* __restrict__ out, int n)
{
    int local = threadIdx.x >> 5;   // 0..7
    int q = threadIdx.x & 31;       // float4 index within row
    int node = blockIdx.x * 8 + local;
    bool active = node < n;
    int s0 = 0, s1 = 0;
    if (active) { s0 = start[node]; s1 = start[node + 1]; }
    int head = q >> 3;
    const float4* __restrict__ h4 = (const float4*)h + q;

    float4 acc = make_float4(0.f, 0.f, 0.f, 0.f);
    int i = s0;
    for (; i + 8 <= s1; i += 8) {
        int   sj[8];
        float aj[8];
#pragma unroll
        for (int j = 0; j < 8; j++) sj[j] = sorted_src[i + j];
#pragma unroll
        for (int j = 0; j < 8; j++) aj[j] = alpha[(i + j) * 4 + head];
        float4 vj[8];
#pragma unroll
        for (int j = 0; j < 8; j++) vj[j] = h4[(size_t)sj[j] * 32];
#pragma unroll
        for (int j = 0; j < 8; j++) {
            acc.x += vj[j].x * aj[j]; acc.y += vj[j].y * aj[j];
            acc.z += vj[j].z * aj[j]; acc.w += vj[j].w * aj[j];
        }
    }
    for (; i < s1; i++) {
        float4 v = h4[(size_t)sorted_src[i] * 32];
        float a = alpha[i * 4 + head];
        acc.x += v.x * a; acc.y += v.y * a; acc.z += v.z * a; acc.w += v.w * a;
    }

    if (MODE == 0) {
        if (active) {
            float4 b4 = ((const float4*)bias)[q];
            float4 v = f4_add(acc, b4);
            v.x = v.x > 0.f ? v.x : (__expf(v.x) - 1.f);
            v.y = v.y > 0.f ? v.y : (__expf(v.y) - 1.f);
            v.z = v.z > 0.f ? v.z : (__expf(v.z) - 1.f);
            v.w = v.w > 0.f ? v.w : (__expf(v.w) - 1.f);
            *(float4*)(out + (size_t)node * 128 + q * 4) = v;
        }
    } else {
        __shared__ float4 sh4[8][33];
        sh4[local][q] = acc;
        __syncthreads();
        if (q < 8 && active) {
            float4 a = sh4[local][q];
            float4 b = sh4[local][q + 8];
            float4 c = sh4[local][q + 16];
            float4 d = sh4[local][q + 24];
            float4 b4 = ((const float4*)bias)[q];
            float4 r = make_float4(0.25f * (a.x + b.x + c.x + d.x) + b4.x,
                                   0.25f * (a.y + b.y + c.y + d.y) + b4.y,
                                   0.25f * (a.z + b.z + c.z + d.z) + b4.z,
                                   0.25f * (a.w + b.w + c.w + d.w) + b4.w);
            *(float4*)(out + (size_t)node * 32 + q * 4) = r;
        }
    }
}

// ---------------------------------------------------------------------------
// Per-node aggregation, F = 32 (layer 1). 8 threads/node (float4), 32
// nodes/block, 8-deep pipeline. Fused bias + ELU.
// ---------------------------------------------------------------------------
__global__ __launch_bounds__(256) void node_agg32_kernel(
    const int* __restrict__ start, const int* __restrict__ sorted_src,
    const float* __restrict__ h, const float* __restrict__ alpha,
    const float* __restrict__ bias, float* __restrict__ out, int n)
{
    int local = threadIdx.x >> 3;   // 0..31
    int q = threadIdx.x & 7;
    int node = blockIdx.x * 32 + local;
    if (node >= n) return;
    int s0 = start[node], s1 = start[node + 1];
    int head = q >> 1;
    const float4* __restrict__ h4 = (const float4*)h + q;

    float4 acc = make_float4(0.f, 0.f, 0.f, 0.f);
    int i = s0;
    for (; i + 8 <= s1; i += 8) {
        int   sj[8];
        float aj[8];
#pragma unroll
        for (int j = 0; j < 8; j++) sj[j] = sorted_src[i + j];
#pragma unroll
        for (int j = 0; j < 8; j++) aj[j] = alpha[(i + j) * 4 + head];
        float4 vj[8];
#pragma unroll
        for (int j = 0; j < 8; j++) vj[j] = h4[(size_t)sj[j] * 8];
#pragma unroll
        for (int j = 0; j < 8; j++) {
            acc.x += vj[j].x * aj[j]; acc.y += vj[j].y * aj[j];
            acc.z += vj[j].z * aj[j]; acc.w += vj[j].w * aj[j];
        }
    }
    for (; i < s1; i++) {
        float4 v = h4[(size_t)sorted_src[i] * 8];
        float a = alpha[i * 4 + head];
        acc.x += v.x * a; acc.y += v.y * a; acc.z += v.z * a; acc.w += v.w * a;
    }
    float4 b4 = ((const float4*)bias)[q];
    float4 v = f4_add(acc, b4);
    v.x = v.x > 0.f ? v.x : (__expf(v.x) - 1.f);
    v.y = v.y > 0.f ? v.y : (__expf(v.y) - 1.f);
    v.z = v.z > 0.f ? v.z : (__expf(v.z) - 1.f);
    v.w = v.w > 0.f ? v.w : (__expf(v.w) - 1.f);
    *(float4*)(out + (size_t)node * 32 + q * 4) = v;
}

// ---------------------------------------------------------------------------

extern "C" void kernel_launch(void* const* d_in, const int* in_sizes, int n_in,
                              void* d_out, int out_size, void* d_ws, size_t ws_size,
                              hipStream_t stream)
{
    const float* x   = (const float*)d_in[0];
    const void*  ei  = d_in[1];
    const float* W1  = (const float*)d_in[2];
    const float* as1 = (const float*)d_in[3];
    const float* ad1 = (const float*)d_in[4];
    const float* b1  = (const float*)d_in[5];
    const float* W2  = (const float*)d_in[6];
    const float* as2 = (const float*)d_in[7];
    const float* ad2 = (const float*)d_in[8];
    const float* b2  = (const float*)d_in[9];
    const float* W3  = (const float*)d_in[10];
    const float* as3 = (const float*)d_in[11];
    const float* ad3 = (const float*)d_in[12];
    const float* b3  = (const float*)d_in[13];
    float* out = (float*)d_out;

    const int N_ = in_sizes[0] / 128;
    const int E_ = in_sizes[1] / 2;

    char* ws = (char*)d_ws;
    size_t off = 0;
    auto alloc = [&](size_t nbytes) -> void* {
        void* p = ws + off;
        off += (nbytes + 255) & ~(size_t)255;
        return p;
    };
    float* h          = (float*)alloc((size_t)N_ * 128 * 4);
    float* x2         = (float*)alloc((size_t)N_ * 32 * 4);
    float* x3         = (float*)alloc((size_t)N_ * 128 * 4);
    float* alpha      = (float*)alloc((size_t)E_ * 4 * 4);
    float* asrc       = (float*)alloc((size_t)N_ * 4 * 4);
    float* adst       = (float*)alloc((size_t)N_ * 4 * 4);
    int*   deg        = (int*)alloc((size_t)N_ * 4);
    int*   start      = (int*)alloc((size_t)(N_ + 1) * 4);
    int*   cursor     = (int*)alloc((size_t)N_ * 4);
    int*   sorted_src = (int*)alloc((size_t)E_ * 4);
    int*   bsum       = (int*)alloc(4096);
    int*   flag       = (int*)alloc(256);

    const int gE   = cdiv(E_, 256);
    const int gW4  = cdiv(N_, 4);    // softmax: 4 nodes/block
    const int gN8  = cdiv(N_, 8);    // agg128: 8 nodes/block
    const int gN32 = cdiv(N_, 32);   // agg32: 32 nodes/block
    const int nSB  = cdiv(N_, 1024); // scan blocks

    // ---- CSR build (once; shared by all 3 layers) ----
    detect_i64_kernel<<<1, 1, 0, stream>>>(ei, E_, N_, flag);
    hipMemsetAsync(deg, 0, (size_t)N_ * 4, stream);
    hist_kernel<<<gE, 256, 0, stream>>>(ei, flag, deg, E_);
    scan_part_kernel<<<nSB, 1024, 0, stream>>>(deg, start, bsum, N_);
    scan_bsum_kernel<<<1, 1024, 0, stream>>>(bsum, nSB);
    scan_add_kernel<<<nSB, 1024, 0, stream>>>(deg, bsum, start, cursor, N_);
    scatter_kernel<<<gE, 256, 0, stream>>>(ei, flag, cursor, sorted_src, E_);

    // ---- Layer 1: 128 -> [4,8] concat=32, ELU ----
    gemm_attn_kernel<128, 32><<<cdiv(N_, 256), 256, 0, stream>>>(x, W1, as1, ad1, h,
                                                                 asrc, adst, N_);
    node_softmax_kernel<<<gW4, 256, 0, stream>>>(start, sorted_src, asrc, adst, alpha, N_);
    node_agg32_kernel<<<gN32, 256, 0, stream>>>(start, sorted_src, h, alpha, b1, x2, N_);

    // ---- Layer 2: 32 -> [4,32] concat=128, ELU ----
    gemm_attn_kernel<32, 128><<<cdiv(N_, 64), 256, 0, stream>>>(x2, W2, as2, ad2, h,
                                                                asrc, adst, N_);
    node_softmax_kernel<<<gW4, 256, 0, stream>>>(start, sorted_src, asrc, adst, alpha, N_);
    node_agg128_kernel<0><<<gN8, 256, 0, stream>>>(start, sorted_src, h, alpha, b2, x3, N_);

    // ---- Layer 3: 128 -> [4,32] mean=32 ----
    gemm_attn_kernel<128, 128><<<cdiv(N_, 64), 256, 0, stream>>>(x3, W3, as3, ad3, h,
                                                                 asrc, adst, N_);
    node_softmax_kernel<<<gW4, 256, 0, stream>>>(start, sorted_src, asrc, adst, alpha, N_);
    node_agg128_kernel<1><<<gN8, 256, 0, stream>>>(start, sorted_src, h, alpha, b3, out, N_);
}

// Round 6
// 432.816 us; speedup vs baseline: 3.2707x; 1.1496x over previous
//
#include <hip/hip_runtime.h>

#define NEG_SLOPE 0.2f

static inline int cdiv(long long a, long long b) { return (int)((a + b - 1) / b); }

// ---------------------------------------------------------------------------
// float4 helpers
// ---------------------------------------------------------------------------
__device__ __forceinline__ float4 f4_add(float4 a, float4 b) {
    return make_float4(a.x + b.x, a.y + b.y, a.z + b.z, a.w + b.w);
}
__device__ __forceinline__ float4 f4_leaky(float4 a) {
    return make_float4(a.x > 0.f ? a.x : NEG_SLOPE * a.x,
                       a.y > 0.f ? a.y : NEG_SLOPE * a.y,
                       a.z > 0.f ? a.z : NEG_SLOPE * a.z,
                       a.w > 0.f ? a.w : NEG_SLOPE * a.w);
}
__device__ __forceinline__ float4 f4_max(float4 a, float4 b) {
    return make_float4(fmaxf(a.x, b.x), fmaxf(a.y, b.y), fmaxf(a.z, b.z),
                       fmaxf(a.w, b.w));
}
__device__ __forceinline__ float4 f4_expsub(float4 e, float4 m) {
    return make_float4(__expf(e.x - m.x), __expf(e.y - m.y), __expf(e.z - m.z),
                       __expf(e.w - m.w));
}
__device__ __forceinline__ float f4_get(float4 v, int i) {
    return i == 0 ? v.x : i == 1 ? v.y : i == 2 ? v.z : v.w;
}

// ---------------------------------------------------------------------------
// int64-vs-int32 edge_index probe (all-in-range as int64 <=> really int64).
// ---------------------------------------------------------------------------
__global__ void detect_i64_kernel(const void* ei_raw, int E_, int n, int* flag)
{
    if (blockIdx.x == 0 && threadIdx.x == 0) {
        const long long* e64 = (const long long*)ei_raw;
        int cnt = E_ < 512 ? E_ : 512;
        int ok = 1;
        for (int i = 0; i < cnt; i++) {
            long long v = e64[i];
            if (v < 0 || v >= n) { ok = 0; break; }
        }
        *flag = ok;
    }
}

__device__ __forceinline__ void load_sd(const void* ei_raw, int is64, int e, int E_,
                                        int& s, int& d)
{
    if (is64) {
        const long long* p = (const long long*)ei_raw;
        s = (int)p[e];
        d = (int)p[E_ + e];
    } else {
        const int* p = (const int*)ei_raw;
        s = p[e];
        d = p[E_ + e];
    }
}

// ---------------------------------------------------------------------------
// CSR build: histogram (also stashes decoded int32 src/dst), parallel scan,
// scatter into dst-sorted order.
// ---------------------------------------------------------------------------
__global__ __launch_bounds__(256) void hist_kernel(const void* __restrict__ ei_raw,
                                                   const int* __restrict__ flag,
                                                   int* __restrict__ deg,
                                                   int* __restrict__ s32,
                                                   int* __restrict__ d32, int E_)
{
    int e = blockIdx.x * 256 + threadIdx.x;
    if (e >= E_) return;
    int is64 = *flag;
    int s, d;
    load_sd(ei_raw, is64, e, E_, s, d);
    s32[e] = s;
    d32[e] = d;
    atomicAdd(deg + d, 1);
}

__device__ __forceinline__ int wave_incl_scan(int v)
{
    int lane = threadIdx.x & 63;
#pragma unroll
    for (int off = 1; off < 64; off <<= 1) {
        int t = __shfl_up(v, off);
        if (lane >= off) v += t;
    }
    return v;
}

__global__ __launch_bounds__(1024) void scan_part_kernel(const int* __restrict__ deg,
                                                         int* __restrict__ start,
                                                         int* __restrict__ bsum, int n)
{
    __shared__ int wsum[16];
    int i = blockIdx.x * 1024 + threadIdx.x;
    int wid = threadIdx.x >> 6, lane = threadIdx.x & 63;
    int v = (i < n) ? deg[i] : 0;
    int incl = wave_incl_scan(v);
    if (lane == 63) wsum[wid] = incl;
    __syncthreads();
    if (wid == 0) {
        int w = (lane < 16) ? wsum[lane] : 0;
        w = wave_incl_scan(w);
        if (lane < 16) wsum[lane] = w;
    }
    __syncthreads();
    int excl = incl - v + (wid ? wsum[wid - 1] : 0);
    if (i < n) start[i] = excl;
    if (threadIdx.x == 1023) bsum[blockIdx.x] = wsum[15];
}

__global__ __launch_bounds__(1024) void scan_bsum_kernel(int* __restrict__ bsum, int nb)
{
    __shared__ int sh[1024];
    int t = threadIdx.x;
    sh[t] = (t < nb) ? bsum[t] : 0;
    __syncthreads();
    for (int off = 1; off < 1024; off <<= 1) {
        int val = (t >= off) ? sh[t - off] : 0;
        __syncthreads();
        sh[t] += val;
        __syncthreads();
    }
    if (t < nb) bsum[t] = t ? sh[t - 1] : 0;
}

__global__ __launch_bounds__(1024) void scan_add_kernel(const int* __restrict__ deg,
                                                        const int* __restrict__ boffs,
                                                        int* __restrict__ start,
                                                        int* __restrict__ cursor, int n)
{
    int i = blockIdx.x * 1024 + threadIdx.x;
    if (i >= n) return;
    int v = start[i] + boffs[blockIdx.x];
    start[i] = v;
    cursor[i] = v;
    if (i == n - 1) start[n] = v + deg[i];
}

__global__ __launch_bounds__(256) void scatter_kernel(const int* __restrict__ s32,
                                                      const int* __restrict__ d32,
                                                      int* __restrict__ cursor,
                                                      int* __restrict__ sorted_src, int E_)
{
    int e = blockIdx.x * 256 + threadIdx.x;
    if (e >= E_) return;
    int pos = atomicAdd(cursor + d32[e], 1);
    sorted_src[pos] = s32[e];
}

// ---------------------------------------------------------------------------
// Tiled fp32 GEMM with fused attention-coefficient epilogue (see Round-5).
// ---------------------------------------------------------------------------
template <int K, int NOUT>
__global__ __launch_bounds__(256) void gemm_attn_kernel(
    const float* __restrict__ x, const float* __restrict__ W,
    const float* __restrict__ att_s, const float* __restrict__ att_d,
    float* __restrict__ h, float* __restrict__ a_s, float* __restrict__ a_d, int n)
{
    constexpr int NPT  = 8;
    constexpr int COLQ = NOUT / 4;
    constexpr int NG   = 256 / COLQ;
    constexpr int MT   = NG * NPT;
    constexpr int KC   = 32;
    constexpr int XLD  = MT + 4;
    constexpr int R    = COLQ / 4;

    __shared__ float Xs[KC][XLD];
    __shared__ float Ws[KC][NOUT];

    const int tid  = threadIdx.x;
    const int colq = tid % COLQ;
    const int ng   = tid / COLQ;
    const int nb   = blockIdx.x * MT;
    const int n0   = ng * NPT;

    float4 acc[NPT];
#pragma unroll
    for (int t = 0; t < NPT; t++) acc[t] = make_float4(0.f, 0.f, 0.f, 0.f);

    for (int kc = 0; kc < K; kc += KC) {
#pragma unroll
        for (int q = tid; q < MT * (KC / 4); q += 256) {
            int node = q / (KC / 4);
            int kq   = q % (KC / 4);
            int gn   = nb + node;
            float4 v = make_float4(0.f, 0.f, 0.f, 0.f);
            if (gn < n) v = *(const float4*)(x + (size_t)gn * K + kc + kq * 4);
            Xs[kq * 4 + 0][node] = v.x;
            Xs[kq * 4 + 1][node] = v.y;
            Xs[kq * 4 + 2][node] = v.z;
            Xs[kq * 4 + 3][node] = v.w;
        }
        const float4* Wg = (const float4*)(W + (size_t)kc * NOUT);
#pragma unroll
        for (int q = tid; q < KC * NOUT / 4; q += 256) {
            ((float4*)&Ws[0][0])[q] = Wg[q];
        }
        __syncthreads();

#pragma unroll
        for (int k = 0; k < KC; k++) {
            float4 w4 = *(const float4*)&Ws[k][colq * 4];
#pragma unroll
            for (int t = 0; t < NPT; t += 4) {
                float4 xv = *(const float4*)&Xs[k][n0 + t];
                acc[t + 0].x += xv.x * w4.x; acc[t + 0].y += xv.x * w4.y;
                acc[t + 0].z += xv.x * w4.z; acc[t + 0].w += xv.x * w4.w;
                acc[t + 1].x += xv.y * w4.x; acc[t + 1].y += xv.y * w4.y;
                acc[t + 1].z += xv.y * w4.z; acc[t + 1].w += xv.y * w4.w;
                acc[t + 2].x += xv.z * w4.x; acc[t + 2].y += xv.z * w4.y;
                acc[t + 2].z += xv.z * w4.z; acc[t + 2].w += xv.z * w4.w;
                acc[t + 3].x += xv.w * w4.x; acc[t + 3].y += xv.w * w4.y;
                acc[t + 3].z += xv.w * w4.z; acc[t + 3].w += xv.w * w4.w;
            }
        }
        __syncthreads();
    }

#pragma unroll
    for (int t = 0; t < NPT; t++) {
        int gn = nb + n0 + t;
        if (gn < n) *(float4*)(h + (size_t)gn * NOUT + colq * 4) = acc[t];
    }

    const float4 avs = ((const float4*)att_s)[colq];
    const float4 avd = ((const float4*)att_d)[colq];
    const int head = colq / R;
    float ps[NPT], pd[NPT];
#pragma unroll
    for (int t = 0; t < NPT; t++) {
        ps[t] = acc[t].x * avs.x + acc[t].y * avs.y + acc[t].z * avs.z + acc[t].w * avs.w;
        pd[t] = acc[t].x * avd.x + acc[t].y * avd.y + acc[t].z * avd.z + acc[t].w * avd.w;
    }
#pragma unroll
    for (int off = R >> 1; off; off >>= 1) {
#pragma unroll
        for (int t = 0; t < NPT; t++) {
            ps[t] += __shfl_xor(ps[t], off);
            pd[t] += __shfl_xor(pd[t], off);
        }
    }
    if (colq % R == 0) {
#pragma unroll
        for (int t = 0; t < NPT; t++) {
            int gn = nb + n0 + t;
            if (gn < n) {
                a_s[gn * 4 + head] = ps[t];
                a_d[gn * 4 + head] = pd[t];
            }
        }
    }
}

// ---------------------------------------------------------------------------
// FUSED softmax + aggregation, F = 128 (layers 2/3).
// 32 threads/node, 8 nodes/block. Phase A: segment softmax over the node's
// edge list (two sweeps of L2-resident a_src table); unnormalized p stashed
// in LDS for deg<=64 (covers ~all nodes at mean deg 16); rare deg>64 nodes
// recompute alpha on the fly in Phase B from (m, 1/s). Phase B: 8-deep
// pipelined 512 B h[src] gathers, alpha from LDS. MODE 0: +bias, ELU.
// MODE 1: head-mean, +bias.
// ---------------------------------------------------------------------------
template <int MODE>
__global__ __launch_bounds__(256) void gat_agg128_kernel(
    const int* __restrict__ start, const int* __restrict__ sorted_src,
    const float* __restrict__ h, const float* __restrict__ a_s,
    const float* __restrict__ a_d, const float* __restrict__ bias,
    float* __restrict__ out, int n)
{
    constexpr int MAXD = 64;
    __shared__ float  p_sh[8][MAXD * 4];
    __shared__ float4 invs_sh[8];
    __shared__ float4 m_sh[8];

    int local = threadIdx.x >> 5;   // node group 0..7
    int q     = threadIdx.x & 31;   // lane within group
    int node  = blockIdx.x * 8 + local;
    bool active = node < n;
    int s0 = 0, s1 = 0;
    if (active) { s0 = start[node]; s1 = start[node + 1]; }
    int deg = s1 - s0;

    const float4* as4 = (const float4*)a_s;
    float4 ad = active ? ((const float4*)a_d)[node] : make_float4(0.f, 0.f, 0.f, 0.f);

    // ---- Phase A: softmax stats (lanes = edges) ----
    float4 mx = make_float4(-INFINITY, -INFINITY, -INFINITY, -INFINITY);
    for (int i = s0 + q; i < s1; i += 32) {
        int s = sorted_src[i];
        mx = f4_max(mx, f4_leaky(f4_add(as4[s], ad)));
    }
#pragma unroll
    for (int off = 16; off; off >>= 1) {
        mx.x = fmaxf(mx.x, __shfl_xor(mx.x, off, 32));
        mx.y = fmaxf(mx.y, __shfl_xor(mx.y, off, 32));
        mx.z = fmaxf(mx.z, __shfl_xor(mx.z, off, 32));
        mx.w = fmaxf(mx.w, __shfl_xor(mx.w, off, 32));
    }
    float4 sm = make_float4(0.f, 0.f, 0.f, 0.f);
    for (int i = s0 + q; i < s1; i += 32) {
        int s = sorted_src[i];
        float4 e = f4_leaky(f4_add(as4[s], ad));
        float4 p = f4_expsub(e, mx);
        sm = f4_add(sm, p);
        int j = i - s0;
        if (j < MAXD) ((float4*)&p_sh[local][0])[j] = p;
    }
#pragma unroll
    for (int off = 16; off; off >>= 1) {
        sm.x += __shfl_xor(sm.x, off, 32);
        sm.y += __shfl_xor(sm.y, off, 32);
        sm.z += __shfl_xor(sm.z, off, 32);
        sm.w += __shfl_xor(sm.w, off, 32);
    }
    if (q == 0) {
        invs_sh[local] = make_float4(1.f / (sm.x + 1e-16f), 1.f / (sm.y + 1e-16f),
                                     1.f / (sm.z + 1e-16f), 1.f / (sm.w + 1e-16f));
        m_sh[local] = mx;
    }
    __syncthreads();

    // ---- Phase B: aggregation (lanes = features) ----
    int head = q >> 3;
    float invh = f4_get(invs_sh[local], head);
    const float4* __restrict__ h4 = (const float4*)h + q;
    const float* __restrict__ pl = &p_sh[local][0];

    float4 acc = make_float4(0.f, 0.f, 0.f, 0.f);
    if (deg <= MAXD) {
        int i = 0;
        for (; i + 8 <= deg; i += 8) {
            int   sj[8];
            float aj[8];
#pragma unroll
            for (int j = 0; j < 8; j++) sj[j] = sorted_src[s0 + i + j];
#pragma unroll
            for (int j = 0; j < 8; j++) aj[j] = pl[(i + j) * 4 + head] * invh;
            float4 vj[8];
#pragma unroll
            for (int j = 0; j < 8; j++) vj[j] = h4[(size_t)sj[j] * 32];
#pragma unroll
            for (int j = 0; j < 8; j++) {
                acc.x += vj[j].x * aj[j]; acc.y += vj[j].y * aj[j];
                acc.z += vj[j].z * aj[j]; acc.w += vj[j].w * aj[j];
            }
        }
        for (; i < deg; i++) {
            float4 v = h4[(size_t)sorted_src[s0 + i] * 32];
            float a = pl[i * 4 + head] * invh;
            acc.x += v.x * a; acc.y += v.y * a; acc.z += v.z * a; acc.w += v.w * a;
        }
    } else {
        // rare: recompute alpha on the fly
        float4 m4 = m_sh[local];
        for (int i = s0; i < s1; i++) {
            int s = sorted_src[i];
            float4 e = f4_leaky(f4_add(as4[s], ad));
            float4 p = f4_expsub(e, m4);
            float a = f4_get(p, head) * invh;
            float4 v = h4[(size_t)s * 32];
            acc.x += v.x * a; acc.y += v.y * a; acc.z += v.z * a; acc.w += v.w * a;
        }
    }

    if (MODE == 0) {
        if (active) {
            float4 b4 = ((const float4*)bias)[q];
            float4 v = f4_add(acc, b4);
            v.x = v.x > 0.f ? v.x : (__expf(v.x) - 1.f);
            v.y = v.y > 0.f ? v.y : (__expf(v.y) - 1.f);
            v.z = v.z > 0.f ? v.z : (__expf(v.z) - 1.f);
            v.w = v.w > 0.f ? v.w : (__expf(v.w) - 1.f);
            *(float4*)(out + (size_t)node * 128 + q * 4) = v;
        }
    } else {
        __shared__ float4 sh4[8][33];
        sh4[local][q] = acc;
        __syncthreads();
        if (q < 8 && active) {
            float4 a = sh4[local][q];
            float4 b = sh4[local][q + 8];
            float4 c = sh4[local][q + 16];
            float4 d = sh4[local][q + 24];
            float4 b4 = ((const float4*)bias)[q];
            float4 r = make_float4(0.25f * (a.x + b.x + c.x + d.x) + b4.x,
                                   0.25f * (a.y + b.y + c.y + d.y) + b4.y,
                                   0.25f * (a.z + b.z + c.z + d.z) + b4.z,
                                   0.25f * (a.w + b.w + c.w + d.w) + b4.w);
            *(float4*)(out + (size_t)node * 32 + q * 4) = r;
        }
    }
}

// ---------------------------------------------------------------------------
// FUSED softmax + aggregation, F = 32 (layer 1). 8 threads/node, 32
// nodes/block, MAXD=32 LDS p-stash (deg>32 fallback ~1-2 nodes expected).
// ---------------------------------------------------------------------------
__global__ __launch_bounds__(256) void gat_agg32_kernel(
    const int* __restrict__ start, const int* __restrict__ sorted_src,
    const float* __restrict__ h, const float* __restrict__ a_s,
    const float* __restrict__ a_d, const float* __restrict__ bias,
    float* __restrict__ out, int n)
{
    constexpr int MAXD = 32;
    __shared__ float  p_sh[32][MAXD * 4];
    __shared__ float4 invs_sh[32];
    __shared__ float4 m_sh[32];

    int local = threadIdx.x >> 3;   // node group 0..31
    int q     = threadIdx.x & 7;
    int node  = blockIdx.x * 32 + local;
    bool active = node < n;
    int s0 = 0, s1 = 0;
    if (active) { s0 = start[node]; s1 = start[node + 1]; }
    int deg = s1 - s0;

    const float4* as4 = (const float4*)a_s;
    float4 ad = active ? ((const float4*)a_d)[node] : make_float4(0.f, 0.f, 0.f, 0.f);

    // ---- Phase A ----
    float4 mx = make_float4(-INFINITY, -INFINITY, -INFINITY, -INFINITY);
    for (int i = s0 + q; i < s1; i += 8) {
        int s = sorted_src[i];
        mx = f4_max(mx, f4_leaky(f4_add(as4[s], ad)));
    }
#pragma unroll
    for (int off = 4; off; off >>= 1) {
        mx.x = fmaxf(mx.x, __shfl_xor(mx.x, off, 8));
        mx.y = fmaxf(mx.y, __shfl_xor(mx.y, off, 8));
        mx.z = fmaxf(mx.z, __shfl_xor(mx.z, off, 8));
        mx.w = fmaxf(mx.w, __shfl_xor(mx.w, off, 8));
    }
    float4 sm = make_float4(0.f, 0.f, 0.f, 0.f);
    for (int i = s0 + q; i < s1; i += 8) {
        int s = sorted_src[i];
        float4 e = f4_leaky(f4_add(as4[s], ad));
        float4 p = f4_expsub(e, mx);
        sm = f4_add(sm, p);
        int j = i - s0;
        if (j < MAXD) ((float4*)&p_sh[local][0])[j] = p;
    }
#pragma unroll
    for (int off = 4; off; off >>= 1) {
        sm.x += __shfl_xor(sm.x, off, 8);
        sm.y += __shfl_xor(sm.y, off, 8);
        sm.z += __shfl_xor(sm.z, off, 8);
        sm.w += __shfl_xor(sm.w, off, 8);
    }
    if (q == 0) {
        invs_sh[local] = make_float4(1.f / (sm.x + 1e-16f), 1.f / (sm.y + 1e-16f),
                                     1.f / (sm.z + 1e-16f), 1.f / (sm.w + 1e-16f));
        m_sh[local] = mx;
    }
    __syncthreads();

    // ---- Phase B ----
    int head = q >> 1;
    float invh = f4_get(invs_sh[local], head);
    const float4* __restrict__ h4 = (const float4*)h + q;
    const float* __restrict__ pl = &p_sh[local][0];

    float4 acc = make_float4(0.f, 0.f, 0.f, 0.f);
    if (deg <= MAXD) {
        int i = 0;
        for (; i + 8 <= deg; i += 8) {
            int   sj[8];
            float aj[8];
#pragma unroll
            for (int j = 0; j < 8; j++) sj[j] = sorted_src[s0 + i + j];
#pragma unroll
            for (int j = 0; j < 8; j++) aj[j] = pl[(i + j) * 4 + head] * invh;
            float4 vj[8];
#pragma unroll
            for (int j = 0; j < 8; j++) vj[j] = h4[(size_t)sj[j] * 8];
#pragma unroll
            for (int j = 0; j < 8; j++) {
                acc.x += vj[j].x * aj[j]; acc.y += vj[j].y * aj[j];
                acc.z += vj[j].z * aj[j]; acc.w += vj[j].w * aj[j];
            }
        }
        for (; i < deg; i++) {
            float4 v = h4[(size_t)sorted_src[s0 + i] * 8];
            float a = pl[i * 4 + head] * invh;
            acc.x += v.x * a; acc.y += v.y * a; acc.z += v.z * a; acc.w += v.w * a;
        }
    } else {
        float4 m4 = m_sh[local];
        for (int i = s0; i < s1; i++) {
            int s = sorted_src[i];
            float4 e = f4_leaky(f4_add(as4[s], ad));
            float4 p = f4_expsub(e, m4);
            float a = f4_get(p, head) * invh;
            float4 v = h4[(size_t)s * 8];
            acc.x += v.x * a; acc.y += v.y * a; acc.z += v.z * a; acc.w += v.w * a;
        }
    }

    if (active) {
        float4 b4 = ((const float4*)bias)[q];
        float4 v = f4_add(acc, b4);
        v.x = v.x > 0.f ? v.x : (__expf(v.x) - 1.f);
        v.y = v.y > 0.f ? v.y : (__expf(v.y) - 1.f);
        v.z = v.z > 0.f ? v.z : (__expf(v.z) - 1.f);
        v.w = v.w > 0.f ? v.w : (__expf(v.w) - 1.f);
        *(float4*)(out + (size_t)node * 32 + q * 4) = v;
    }
}

// ---------------------------------------------------------------------------

extern "C" void kernel_launch(void* const* d_in, const int* in_sizes, int n_in,
                              void* d_out, int out_size, void* d_ws, size_t ws_size,
                              hipStream_t stream)
{
    const float* x   = (const float*)d_in[0];
    const void*  ei  = d_in[1];
    const float* W1  = (const float*)d_in[2];
    const float* as1 = (const float*)d_in[3];
    const float* ad1 = (const float*)d_in[4];
    const float* b1  = (const float*)d_in[5];
    const float* W2  = (const float*)d_in[6];
    const float* as2 = (const float*)d_in[7];
    const float* ad2 = (const float*)d_in[8];
    const float* b2  = (const float*)d_in[9];
    const float* W3  = (const float*)d_in[10];
    const float* as3 = (const float*)d_in[11];
    const float* ad3 = (const float*)d_in[12];
    const float* b3  = (const float*)d_in[13];
    float* out = (float*)d_out;

    const int N_ = in_sizes[0] / 128;
    const int E_ = in_sizes[1] / 2;

    char* ws = (char*)d_ws;
    size_t off = 0;
    auto alloc = [&](size_t nbytes) -> void* {
        void* p = ws + off;
        off += (nbytes + 255) & ~(size_t)255;
        return p;
    };
    float* h          = (float*)alloc((size_t)N_ * 128 * 4);
    float* x2         = (float*)alloc((size_t)N_ * 32 * 4);
    float* x3         = (float*)alloc((size_t)N_ * 128 * 4);
    float* asrc       = (float*)alloc((size_t)N_ * 4 * 4);
    float* adst       = (float*)alloc((size_t)N_ * 4 * 4);
    int*   deg        = (int*)alloc((size_t)N_ * 4);
    int*   start      = (int*)alloc((size_t)(N_ + 1) * 4);
    int*   cursor     = (int*)alloc((size_t)N_ * 4);
    int*   sorted_src = (int*)alloc((size_t)E_ * 4);
    int*   s32        = (int*)alloc((size_t)E_ * 4);
    int*   d32        = (int*)alloc((size_t)E_ * 4);
    int*   bsum       = (int*)alloc(4096);
    int*   flag       = (int*)alloc(256);

    const int gE   = cdiv(E_, 256);
    const int gN8  = cdiv(N_, 8);    // agg128: 8 nodes/block
    const int gN32 = cdiv(N_, 32);   // agg32: 32 nodes/block
    const int nSB  = cdiv(N_, 1024); // scan blocks

    // ---- CSR build (once; shared by all 3 layers) ----
    detect_i64_kernel<<<1, 1, 0, stream>>>(ei, E_, N_, flag);
    hipMemsetAsync(deg, 0, (size_t)N_ * 4, stream);
    hist_kernel<<<gE, 256, 0, stream>>>(ei, flag, deg, s32, d32, E_);
    scan_part_kernel<<<nSB, 1024, 0, stream>>>(deg, start, bsum, N_);
    scan_bsum_kernel<<<1, 1024, 0, stream>>>(bsum, nSB);
    scan_add_kernel<<<nSB, 1024, 0, stream>>>(deg, bsum, start, cursor, N_);
    scatter_kernel<<<gE, 256, 0, stream>>>(s32, d32, cursor, sorted_src, E_);

    // ---- Layer 1: 128 -> [4,8] concat=32, ELU ----
    gemm_attn_kernel<128, 32><<<cdiv(N_, 256), 256, 0, stream>>>(x, W1, as1, ad1, h,
                                                                 asrc, adst, N_);
    gat_agg32_kernel<<<gN32, 256, 0, stream>>>(start, sorted_src, h, asrc, adst, b1,
                                               x2, N_);

    // ---- Layer 2: 32 -> [4,32] concat=128, ELU ----
    gemm_attn_kernel<32, 128><<<cdiv(N_, 64), 256, 0, stream>>>(x2, W2, as2, ad2, h,
                                                                asrc, adst, N_);
    gat_agg128_kernel<0><<<gN8, 256, 0, stream>>>(start, sorted_src, h, asrc, adst, b2,
                                                  x3, N_);

    // ---- Layer 3: 128 -> [4,32] mean=32 ----
    gemm_attn_kernel<128, 128><<<cdiv(N_, 64), 256, 0, stream>>>(x3, W3, as3, ad3, h,
                                                                 asrc, adst, N_);
    gat_agg128_kernel<1><<<gN8, 256, 0, stream>>>(start, sorted_src, h, asrc, adst, b3,
                                                  out, N_);
}

// Round 7
// 386.055 us; speedup vs baseline: 3.6668x; 1.1211x over previous
//
#include <hip/hip_runtime.h>
#include <hip/hip_fp16.h>

#define NEG_SLOPE 0.2f

static inline int cdiv(long long a, long long b) { return (int)((a + b - 1) / b); }

// ---------------------------------------------------------------------------
// float4 helpers
// ---------------------------------------------------------------------------
__device__ __forceinline__ float4 f4_add(float4 a, float4 b) {
    return make_float4(a.x + b.x, a.y + b.y, a.z + b.z, a.w + b.w);
}
__device__ __forceinline__ float4 f4_leaky(float4 a) {
    return make_float4(a.x > 0.f ? a.x : NEG_SLOPE * a.x,
                       a.y > 0.f ? a.y : NEG_SLOPE * a.y,
                       a.z > 0.f ? a.z : NEG_SLOPE * a.z,
                       a.w > 0.f ? a.w : NEG_SLOPE * a.w);
}
__device__ __forceinline__ float4 f4_exp(float4 e) {
    return make_float4(__expf(e.x), __expf(e.y), __expf(e.z), __expf(e.w));
}
__device__ __forceinline__ float f4_get(float4 v, int i) {
    return i == 0 ? v.x : i == 1 ? v.y : i == 2 ? v.z : v.w;
}

// unpack 4 halves (stored as float2 bits) -> 2x float2
union h4u {
    float2  f2;
    __half2 h2[2];
};

// ---------------------------------------------------------------------------
// int64-vs-int32 edge_index probe (all-in-range as int64 <=> really int64).
// ---------------------------------------------------------------------------
__global__ void detect_i64_kernel(const void* ei_raw, int E_, int n, int* flag)
{
    if (blockIdx.x == 0 && threadIdx.x == 0) {
        const long long* e64 = (const long long*)ei_raw;
        int cnt = E_ < 512 ? E_ : 512;
        int ok = 1;
        for (int i = 0; i < cnt; i++) {
            long long v = e64[i];
            if (v < 0 || v >= n) { ok = 0; break; }
        }
        *flag = ok;
    }
}

__device__ __forceinline__ void load_sd(const void* ei_raw, int is64, int e, int E_,
                                        int& s, int& d)
{
    if (is64) {
        const long long* p = (const long long*)ei_raw;
        s = (int)p[e];
        d = (int)p[E_ + e];
    } else {
        const int* p = (const int*)ei_raw;
        s = p[e];
        d = p[E_ + e];
    }
}

// ---------------------------------------------------------------------------
// CSR build: histogram (stashes decoded int32 src/dst), parallel scan, scatter.
// ---------------------------------------------------------------------------
__global__ __launch_bounds__(256) void hist_kernel(const void* __restrict__ ei_raw,
                                                   const int* __restrict__ flag,
                                                   int* __restrict__ deg,
                                                   int* __restrict__ s32,
                                                   int* __restrict__ d32, int E_)
{
    int e = blockIdx.x * 256 + threadIdx.x;
    if (e >= E_) return;
    int is64 = *flag;
    int s, d;
    load_sd(ei_raw, is64, e, E_, s, d);
    s32[e] = s;
    d32[e] = d;
    atomicAdd(deg + d, 1);
}

__device__ __forceinline__ int wave_incl_scan(int v)
{
    int lane = threadIdx.x & 63;
#pragma unroll
    for (int off = 1; off < 64; off <<= 1) {
        int t = __shfl_up(v, off);
        if (lane >= off) v += t;
    }
    return v;
}

__global__ __launch_bounds__(1024) void scan_part_kernel(const int* __restrict__ deg,
                                                         int* __restrict__ start,
                                                         int* __restrict__ bsum, int n)
{
    __shared__ int wsum[16];
    int i = blockIdx.x * 1024 + threadIdx.x;
    int wid = threadIdx.x >> 6, lane = threadIdx.x & 63;
    int v = (i < n) ? deg[i] : 0;
    int incl = wave_incl_scan(v);
    if (lane == 63) wsum[wid] = incl;
    __syncthreads();
    if (wid == 0) {
        int w = (lane < 16) ? wsum[lane] : 0;
        w = wave_incl_scan(w);
        if (lane < 16) wsum[lane] = w;
    }
    __syncthreads();
    int excl = incl - v + (wid ? wsum[wid - 1] : 0);
    if (i < n) start[i] = excl;
    if (threadIdx.x == 1023) bsum[blockIdx.x] = wsum[15];
}

__global__ __launch_bounds__(1024) void scan_bsum_kernel(int* __restrict__ bsum, int nb)
{
    __shared__ int sh[1024];
    int t = threadIdx.x;
    sh[t] = (t < nb) ? bsum[t] : 0;
    __syncthreads();
    for (int off = 1; off < 1024; off <<= 1) {
        int val = (t >= off) ? sh[t - off] : 0;
        __syncthreads();
        sh[t] += val;
        __syncthreads();
    }
    if (t < nb) bsum[t] = t ? sh[t - 1] : 0;
}

__global__ __launch_bounds__(1024) void scan_add_kernel(const int* __restrict__ deg,
                                                        const int* __restrict__ boffs,
                                                        int* __restrict__ start,
                                                        int* __restrict__ cursor, int n)
{
    int i = blockIdx.x * 1024 + threadIdx.x;
    if (i >= n) return;
    int v = start[i] + boffs[blockIdx.x];
    start[i] = v;
    cursor[i] = v;
    if (i == n - 1) start[n] = v + deg[i];
}

__global__ __launch_bounds__(256) void scatter_kernel(const int* __restrict__ s32,
                                                      const int* __restrict__ d32,
                                                      int* __restrict__ cursor,
                                                      int* __restrict__ sorted_src, int E_)
{
    int e = blockIdx.x * 256 + threadIdx.x;
    if (e >= E_) return;
    int pos = atomicAdd(cursor + d32[e], 1);
    sorted_src[pos] = s32[e];
}

// ---------------------------------------------------------------------------
// Tiled fp32 GEMM + fused attention epilogue; h stored FP16 (gather table).
// ---------------------------------------------------------------------------
template <int K, int NOUT>
__global__ __launch_bounds__(256) void gemm_attn_kernel(
    const float* __restrict__ x, const float* __restrict__ W,
    const float* __restrict__ att_s, const float* __restrict__ att_d,
    __half* __restrict__ h, float* __restrict__ a_s, float* __restrict__ a_d, int n)
{
    constexpr int NPT  = 8;
    constexpr int COLQ = NOUT / 4;
    constexpr int NG   = 256 / COLQ;
    constexpr int MT   = NG * NPT;
    constexpr int KC   = 32;
    constexpr int XLD  = MT + 4;
    constexpr int R    = COLQ / 4;

    __shared__ float Xs[KC][XLD];
    __shared__ float Ws[KC][NOUT];

    const int tid  = threadIdx.x;
    const int colq = tid % COLQ;
    const int ng   = tid / COLQ;
    const int nb   = blockIdx.x * MT;
    const int n0   = ng * NPT;

    float4 acc[NPT];
#pragma unroll
    for (int t = 0; t < NPT; t++) acc[t] = make_float4(0.f, 0.f, 0.f, 0.f);

    for (int kc = 0; kc < K; kc += KC) {
#pragma unroll
        for (int q = tid; q < MT * (KC / 4); q += 256) {
            int node = q / (KC / 4);
            int kq   = q % (KC / 4);
            int gn   = nb + node;
            float4 v = make_float4(0.f, 0.f, 0.f, 0.f);
            if (gn < n) v = *(const float4*)(x + (size_t)gn * K + kc + kq * 4);
            Xs[kq * 4 + 0][node] = v.x;
            Xs[kq * 4 + 1][node] = v.y;
            Xs[kq * 4 + 2][node] = v.z;
            Xs[kq * 4 + 3][node] = v.w;
        }
        const float4* Wg = (const float4*)(W + (size_t)kc * NOUT);
#pragma unroll
        for (int q = tid; q < KC * NOUT / 4; q += 256) {
            ((float4*)&Ws[0][0])[q] = Wg[q];
        }
        __syncthreads();

#pragma unroll
        for (int k = 0; k < KC; k++) {
            float4 w4 = *(const float4*)&Ws[k][colq * 4];
#pragma unroll
            for (int t = 0; t < NPT; t += 4) {
                float4 xv = *(const float4*)&Xs[k][n0 + t];
                acc[t + 0].x += xv.x * w4.x; acc[t + 0].y += xv.x * w4.y;
                acc[t + 0].z += xv.x * w4.z; acc[t + 0].w += xv.x * w4.w;
                acc[t + 1].x += xv.y * w4.x; acc[t + 1].y += xv.y * w4.y;
                acc[t + 1].z += xv.y * w4.z; acc[t + 1].w += xv.y * w4.w;
                acc[t + 2].x += xv.z * w4.x; acc[t + 2].y += xv.z * w4.y;
                acc[t + 2].z += xv.z * w4.z; acc[t + 2].w += xv.z * w4.w;
                acc[t + 3].x += xv.w * w4.x; acc[t + 3].y += xv.w * w4.y;
                acc[t + 3].z += xv.w * w4.z; acc[t + 3].w += xv.w * w4.w;
            }
        }
        __syncthreads();
    }

    // ---- h store (fp16, 8 B per thread per node) ----
#pragma unroll
    for (int t = 0; t < NPT; t++) {
        int gn = nb + n0 + t;
        if (gn < n) {
            h4u u;
            u.h2[0] = __floats2half2_rn(acc[t].x, acc[t].y);
            u.h2[1] = __floats2half2_rn(acc[t].z, acc[t].w);
            *(float2*)(h + (size_t)gn * NOUT + colq * 4) = u.f2;
        }
    }

    // ---- fused attention coefficients (fp32 acc) ----
    const float4 avs = ((const float4*)att_s)[colq];
    const float4 avd = ((const float4*)att_d)[colq];
    const int head = colq / R;
    float ps[NPT], pd[NPT];
#pragma unroll
    for (int t = 0; t < NPT; t++) {
        ps[t] = acc[t].x * avs.x + acc[t].y * avs.y + acc[t].z * avs.z + acc[t].w * avs.w;
        pd[t] = acc[t].x * avd.x + acc[t].y * avd.y + acc[t].z * avd.z + acc[t].w * avd.w;
    }
#pragma unroll
    for (int off = R >> 1; off; off >>= 1) {
#pragma unroll
        for (int t = 0; t < NPT; t++) {
            ps[t] += __shfl_xor(ps[t], off);
            pd[t] += __shfl_xor(pd[t], off);
        }
    }
    if (colq % R == 0) {
#pragma unroll
        for (int t = 0; t < NPT; t++) {
            int gn = nb + n0 + t;
            if (gn < n) {
                a_s[gn * 4 + head] = ps[t];
                a_d[gn * 4 + head] = pd[t];
            }
        }
    }
}

// ---------------------------------------------------------------------------
// FUSED softmax + aggregation, F = 128 (layers 2/3). 32 thr/node, 8
// nodes/block. Single-sweep softmax: p = exp(e) directly (logits bounded,
// shift-invariant — max pass removed), p stashed in LDS for deg<=64.
// Phase B: 8-deep pipelined fp16 gathers (8 B/lane = 4 features).
// MODE 0: +bias, ELU (fp32 out). MODE 1: head-mean, +bias.
// ---------------------------------------------------------------------------
template <int MODE>
__global__ __launch_bounds__(256) void gat_agg128_kernel(
    const int* __restrict__ start, const int* __restrict__ sorted_src,
    const __half* __restrict__ h, const float* __restrict__ a_s,
    const float* __restrict__ a_d, const float* __restrict__ bias,
    float* __restrict__ out, int n)
{
    constexpr int MAXD = 64;
    __shared__ float  p_sh[8][MAXD * 4];
    __shared__ float4 invs_sh[8];

    int local = threadIdx.x >> 5;
    int q     = threadIdx.x & 31;
    int node  = blockIdx.x * 8 + local;
    bool active = node < n;
    int s0 = 0, s1 = 0;
    if (active) { s0 = start[node]; s1 = start[node + 1]; }
    int deg = s1 - s0;

    const float4* as4 = (const float4*)a_s;
    float4 ad = active ? ((const float4*)a_d)[node] : make_float4(0.f, 0.f, 0.f, 0.f);

    // ---- Phase A: single sweep, p = exp(e) ----
    float4 sm = make_float4(0.f, 0.f, 0.f, 0.f);
    for (int i = s0 + q; i < s1; i += 32) {
        int s = sorted_src[i];
        float4 p = f4_exp(f4_leaky(f4_add(as4[s], ad)));
        sm = f4_add(sm, p);
        int j = i - s0;
        if (j < MAXD) ((float4*)&p_sh[local][0])[j] = p;
    }
#pragma unroll
    for (int off = 16; off; off >>= 1) {
        sm.x += __shfl_xor(sm.x, off, 32);
        sm.y += __shfl_xor(sm.y, off, 32);
        sm.z += __shfl_xor(sm.z, off, 32);
        sm.w += __shfl_xor(sm.w, off, 32);
    }
    if (q == 0) {
        invs_sh[local] = make_float4(1.f / (sm.x + 1e-16f), 1.f / (sm.y + 1e-16f),
                                     1.f / (sm.z + 1e-16f), 1.f / (sm.w + 1e-16f));
    }
    __syncthreads();

    // ---- Phase B: aggregation; lane q owns features 4q..4q+3 ----
    int head = q >> 3;
    float invh = f4_get(invs_sh[local], head);
    const float2* __restrict__ h2 = (const float2*)h + q;  // 8 B units
    const float* __restrict__ pl = &p_sh[local][0];

    float4 acc = make_float4(0.f, 0.f, 0.f, 0.f);
    if (deg <= MAXD) {
        int i = 0;
        for (; i + 8 <= deg; i += 8) {
            int   sj[8];
            float aj[8];
#pragma unroll
            for (int j = 0; j < 8; j++) sj[j] = sorted_src[s0 + i + j];
#pragma unroll
            for (int j = 0; j < 8; j++) aj[j] = pl[(i + j) * 4 + head] * invh;
            float2 rj[8];
#pragma unroll
            for (int j = 0; j < 8; j++) rj[j] = h2[(size_t)sj[j] * 32];
#pragma unroll
            for (int j = 0; j < 8; j++) {
                h4u u; u.f2 = rj[j];
                float2 lo = __half22float2(u.h2[0]);
                float2 hi = __half22float2(u.h2[1]);
                acc.x += lo.x * aj[j]; acc.y += lo.y * aj[j];
                acc.z += hi.x * aj[j]; acc.w += hi.y * aj[j];
            }
        }
        for (; i < deg; i++) {
            h4u u; u.f2 = h2[(size_t)sorted_src[s0 + i] * 32];
            float a = pl[i * 4 + head] * invh;
            float2 lo = __half22float2(u.h2[0]);
            float2 hi = __half22float2(u.h2[1]);
            acc.x += lo.x * a; acc.y += lo.y * a; acc.z += hi.x * a; acc.w += hi.y * a;
        }
    } else {
        // rare big-degree fallback: recompute p on the fly
        for (int i = s0; i < s1; i++) {
            int s = sorted_src[i];
            float4 p = f4_exp(f4_leaky(f4_add(as4[s], ad)));
            float a = f4_get(p, head) * invh;
            h4u u; u.f2 = h2[(size_t)s * 32];
            float2 lo = __half22float2(u.h2[0]);
            float2 hi = __half22float2(u.h2[1]);
            acc.x += lo.x * a; acc.y += lo.y * a; acc.z += hi.x * a; acc.w += hi.y * a;
        }
    }

    if (MODE == 0) {
        if (active) {
            float4 b4 = ((const float4*)bias)[q];
            float4 v = f4_add(acc, b4);
            v.x = v.x > 0.f ? v.x : (__expf(v.x) - 1.f);
            v.y = v.y > 0.f ? v.y : (__expf(v.y) - 1.f);
            v.z = v.z > 0.f ? v.z : (__expf(v.z) - 1.f);
            v.w = v.w > 0.f ? v.w : (__expf(v.w) - 1.f);
            *(float4*)(out + (size_t)node * 128 + q * 4) = v;
        }
    } else {
        __shared__ float4 sh4[8][33];
        sh4[local][q] = acc;
        __syncthreads();
        if (q < 8 && active) {
            float4 a = sh4[local][q];
            float4 b = sh4[local][q + 8];
            float4 c = sh4[local][q + 16];
            float4 d = sh4[local][q + 24];
            float4 b4 = ((const float4*)bias)[q];
            float4 r = make_float4(0.25f * (a.x + b.x + c.x + d.x) + b4.x,
                                   0.25f * (a.y + b.y + c.y + d.y) + b4.y,
                                   0.25f * (a.z + b.z + c.z + d.z) + b4.z,
                                   0.25f * (a.w + b.w + c.w + d.w) + b4.w);
            *(float4*)(out + (size_t)node * 32 + q * 4) = r;
        }
    }
}

// ---------------------------------------------------------------------------
// FUSED softmax + aggregation, F = 32 (layer 1). 8 thr/node, 32 nodes/block.
// ---------------------------------------------------------------------------
__global__ __launch_bounds__(256) void gat_agg32_kernel(
    const int* __restrict__ start, const int* __restrict__ sorted_src,
    const __half* __restrict__ h, const float* __restrict__ a_s,
    const float* __restrict__ a_d, const float* __restrict__ bias,
    float* __restrict__ out, int n)
{
    constexpr int MAXD = 32;
    __shared__ float  p_sh[32][MAXD * 4];
    __shared__ float4 invs_sh[32];

    int local = threadIdx.x >> 3;
    int q     = threadIdx.x & 7;
    int node  = blockIdx.x * 32 + local;
    bool active = node < n;
    int s0 = 0, s1 = 0;
    if (active) { s0 = start[node]; s1 = start[node + 1]; }
    int deg = s1 - s0;

    const float4* as4 = (const float4*)a_s;
    float4 ad = active ? ((const float4*)a_d)[node] : make_float4(0.f, 0.f, 0.f, 0.f);

    // ---- Phase A ----
    float4 sm = make_float4(0.f, 0.f, 0.f, 0.f);
    for (int i = s0 + q; i < s1; i += 8) {
        int s = sorted_src[i];
        float4 p = f4_exp(f4_leaky(f4_add(as4[s], ad)));
        sm = f4_add(sm, p);
        int j = i - s0;
        if (j < MAXD) ((float4*)&p_sh[local][0])[j] = p;
    }
#pragma unroll
    for (int off = 4; off; off >>= 1) {
        sm.x += __shfl_xor(sm.x, off, 8);
        sm.y += __shfl_xor(sm.y, off, 8);
        sm.z += __shfl_xor(sm.z, off, 8);
        sm.w += __shfl_xor(sm.w, off, 8);
    }
    if (q == 0) {
        invs_sh[local] = make_float4(1.f / (sm.x + 1e-16f), 1.f / (sm.y + 1e-16f),
                                     1.f / (sm.z + 1e-16f), 1.f / (sm.w + 1e-16f));
    }
    __syncthreads();

    // ---- Phase B ----
    int head = q >> 1;
    float invh = f4_get(invs_sh[local], head);
    const float2* __restrict__ h2 = (const float2*)h + q;  // 8 B units
    const float* __restrict__ pl = &p_sh[local][0];

    float4 acc = make_float4(0.f, 0.f, 0.f, 0.f);
    if (deg <= MAXD) {
        int i = 0;
        for (; i + 8 <= deg; i += 8) {
            int   sj[8];
            float aj[8];
#pragma unroll
            for (int j = 0; j < 8; j++) sj[j] = sorted_src[s0 + i + j];
#pragma unroll
            for (int j = 0; j < 8; j++) aj[j] = pl[(i + j) * 4 + head] * invh;
            float2 rj[8];
#pragma unroll
            for (int j = 0; j < 8; j++) rj[j] = h2[(size_t)sj[j] * 8];
#pragma unroll
            for (int j = 0; j < 8; j++) {
                h4u u; u.f2 = rj[j];
                float2 lo = __half22float2(u.h2[0]);
                float2 hi = __half22float2(u.h2[1]);
                acc.x += lo.x * aj[j]; acc.y += lo.y * aj[j];
                acc.z += hi.x * aj[j]; acc.w += hi.y * aj[j];
            }
        }
        for (; i < deg; i++) {
            h4u u; u.f2 = h2[(size_t)sorted_src[s0 + i] * 8];
            float a = pl[i * 4 + head] * invh;
            float2 lo = __half22float2(u.h2[0]);
            float2 hi = __half22float2(u.h2[1]);
            acc.x += lo.x * a; acc.y += lo.y * a; acc.z += hi.x * a; acc.w += hi.y * a;
        }
    } else {
        for (int i = s0; i < s1; i++) {
            int s = sorted_src[i];
            float4 p = f4_exp(f4_leaky(f4_add(as4[s], ad)));
            float a = f4_get(p, head) * invh;
            h4u u; u.f2 = h2[(size_t)s * 8];
            float2 lo = __half22float2(u.h2[0]);
            float2 hi = __half22float2(u.h2[1]);
            acc.x += lo.x * a; acc.y += lo.y * a; acc.z += hi.x * a; acc.w += hi.y * a;
        }
    }

    if (active) {
        float4 b4 = ((const float4*)bias)[q];
        float4 v = f4_add(acc, b4);
        v.x = v.x > 0.f ? v.x : (__expf(v.x) - 1.f);
        v.y = v.y > 0.f ? v.y : (__expf(v.y) - 1.f);
        v.z = v.z > 0.f ? v.z : (__expf(v.z) - 1.f);
        v.w = v.w > 0.f ? v.w : (__expf(v.w) - 1.f);
        *(float4*)(out + (size_t)node * 32 + q * 4) = v;
    }
}

// ---------------------------------------------------------------------------

extern "C" void kernel_launch(void* const* d_in, const int* in_sizes, int n_in,
                              void* d_out, int out_size, void* d_ws, size_t ws_size,
                              hipStream_t stream)
{
    const float* x   = (const float*)d_in[0];
    const void*  ei  = d_in[1];
    const float* W1  = (const float*)d_in[2];
    const float* as1 = (const float*)d_in[3];
    const float* ad1 = (const float*)d_in[4];
    const float* b1  = (const float*)d_in[5];
    const float* W2  = (const float*)d_in[6];
    const float* as2 = (const float*)d_in[7];
    const float* ad2 = (const float*)d_in[8];
    const float* b2  = (const float*)d_in[9];
    const float* W3  = (const float*)d_in[10];
    const float* as3 = (const float*)d_in[11];
    const float* ad3 = (const float*)d_in[12];
    const float* b3  = (const float*)d_in[13];
    float* out = (float*)d_out;

    const int N_ = in_sizes[0] / 128;
    const int E_ = in_sizes[1] / 2;

    char* ws = (char*)d_ws;
    size_t off = 0;
    auto alloc = [&](size_t nbytes) -> void* {
        void* p = ws + off;
        off += (nbytes + 255) & ~(size_t)255;
        return p;
    };
    __half* h         = (__half*)alloc((size_t)N_ * 128 * 2);
    float* x2         = (float*)alloc((size_t)N_ * 32 * 4);
    float* x3         = (float*)alloc((size_t)N_ * 128 * 4);
    float* asrc       = (float*)alloc((size_t)N_ * 4 * 4);
    float* adst       = (float*)alloc((size_t)N_ * 4 * 4);
    int*   deg        = (int*)alloc((size_t)N_ * 4);
    int*   start      = (int*)alloc((size_t)(N_ + 1) * 4);
    int*   cursor     = (int*)alloc((size_t)N_ * 4);
    int*   sorted_src = (int*)alloc((size_t)E_ * 4);
    int*   s32        = (int*)alloc((size_t)E_ * 4);
    int*   d32        = (int*)alloc((size_t)E_ * 4);
    int*   bsum       = (int*)alloc(4096);
    int*   flag       = (int*)alloc(256);

    const int gE   = cdiv(E_, 256);
    const int gN8  = cdiv(N_, 8);
    const int gN32 = cdiv(N_, 32);
    const int nSB  = cdiv(N_, 1024);

    // ---- CSR build (once; shared by all 3 layers) ----
    detect_i64_kernel<<<1, 1, 0, stream>>>(ei, E_, N_, flag);
    hipMemsetAsync(deg, 0, (size_t)N_ * 4, stream);
    hist_kernel<<<gE, 256, 0, stream>>>(ei, flag, deg, s32, d32, E_);
    scan_part_kernel<<<nSB, 1024, 0, stream>>>(deg, start, bsum, N_);
    scan_bsum_kernel<<<1, 1024, 0, stream>>>(bsum, nSB);
    scan_add_kernel<<<nSB, 1024, 0, stream>>>(deg, bsum, start, cursor, N_);
    scatter_kernel<<<gE, 256, 0, stream>>>(s32, d32, cursor, sorted_src, E_);

    // ---- Layer 1: 128 -> [4,8] concat=32, ELU ----
    gemm_attn_kernel<128, 32><<<cdiv(N_, 256), 256, 0, stream>>>(x, W1, as1, ad1, h,
                                                                 asrc, adst, N_);
    gat_agg32_kernel<<<gN32, 256, 0, stream>>>(start, sorted_src, h, asrc, adst, b1,
                                               x2, N_);

    // ---- Layer 2: 32 -> [4,32] concat=128, ELU ----
    gemm_attn_kernel<32, 128><<<cdiv(N_, 64), 256, 0, stream>>>(x2, W2, as2, ad2, h,
                                                                asrc, adst, N_);
    gat_agg128_kernel<0><<<gN8, 256, 0, stream>>>(start, sorted_src, h, asrc, adst, b2,
                                                  x3, N_);

    // ---- Layer 3: 128 -> [4,32] mean=32 ----
    gemm_attn_kernel<128, 128><<<cdiv(N_, 64), 256, 0, stream>>>(x3, W3, as3, ad3, h,
                                                                 asrc, adst, N_);
    gat_agg128_kernel<1><<<gN8, 256, 0, stream>>>(start, sorted_src, h, asrc, adst, b3,
                                                  out, N_);
}